// Round 14
// baseline (252.441 us; speedup 1.0000x reference)
//
#include <hip/hip_runtime.h>
#include <hip/hip_bf16.h>
#include <cstdint>

typedef _Float16 f16;
typedef _Float16 half8 __attribute__((ext_vector_type(8)));
typedef float f32x4 __attribute__((ext_vector_type(4)));

#define SCALE 0.125f

// async global->LDS, 16B per lane, dest = wave-uniform base + lane*16
#define GLL(src, dst) __builtin_amdgcn_global_load_lds( \
    (const __attribute__((address_space(1))) unsigned int*)(src), \
    (__attribute__((address_space(3))) unsigned int*)(dst), 16, 0, 0)

// ---------------- prep: x (64,256,1024) f32 -> xT (64,1024,256) f16 ----------------
__global__ __launch_bounds__(256) void prep_xT(const float* __restrict__ x, f16* __restrict__ xT) {
  __shared__ f16 tile[32][33];
  int b = blockIdx.z, nt = blockIdx.y, dt = blockIdx.x;
  int c = threadIdx.x & 31, rp = threadIdx.x >> 5;
  const float* xb = x + ((size_t)b*256 + nt*32)*1024 + dt*32;
#pragma unroll
  for (int p = 0; p < 4; ++p) { int r = p*8 + rp; tile[r][c] = (f16)xb[(size_t)r*1024 + c]; }
  __syncthreads();
  f16* o = xT + ((size_t)b*1024 + dt*32)*256 + nt*32;
#pragma unroll
  for (int p = 0; p < 4; ++p) { int r = p*8 + rp; o[(size_t)r*256 + c] = tile[c][r]; }
}

// ---------------- prep: Wspec (256,768) f32 -> Wspec16 [256][512] f16 (first 512 cols) ----
__global__ __launch_bounds__(256) void prep_Wspec16(const float* __restrict__ W, f16* __restrict__ Wt) {
  int row = blockIdx.x, t = threadIdx.x;
  Wt[(size_t)row*512 + t]       = (f16)W[(size_t)row*768 + t];
  Wt[(size_t)row*512 + 256 + t] = (f16)W[(size_t)row*768 + 256 + t];
}

// ---------------- 128x128x(32*KSTEPS) f16 GEMM, double-buffered + counted vmcnt ----
template<int KSTEPS, int AST, int BST, int CST, bool SCALEQ>
__global__ __launch_bounds__(256) void gemm128(const f16* __restrict__ Ag, const f16* __restrict__ Bg,
                                               f16* __restrict__ Cg, size_t aB, size_t bB, size_t cB) {
  __shared__ f16 As[2][128*32];
  __shared__ f16 Bs[2][128*32];
  const f16* A = Ag + (size_t)blockIdx.z*aB;
  const f16* B = Bg + (size_t)blockIdx.z*bB;
  f16* C = Cg + (size_t)blockIdx.z*cB;
  int t = threadIdx.x, lane = t & 63, wave = t >> 6;
  int l15 = lane & 15, l4 = lane >> 4;
  int wm = wave & 1, wn = wave >> 1;
  size_t m0 = (size_t)blockIdx.x*128, n0 = (size_t)blockIdx.y*128;
  f32x4 acc[4][4];
#pragma unroll
  for (int i=0;i<4;++i)
#pragma unroll
    for (int j=0;j<4;++j) acc[i][j] = (f32x4){0.f,0.f,0.f,0.f};
  int rowS[2], chS[2];
#pragma unroll
  for (int c=0;c<2;++c) {
    int slot = c*256 + t;
    rowS[c] = slot >> 2;
    chS[c]  = (slot & 3) ^ ((slot >> 3) & 3);
  }
  int pc = (l4 ^ ((l15 >> 1) & 3)) * 8;

  auto STAGE = [&](int buf, int ks) {
    int k0 = ks*32;
#pragma unroll
    for (int c=0;c<2;++c) {
      GLL(A + (m0 + rowS[c])*(size_t)AST + k0 + chS[c]*8, &As[buf][(c*256 + wave*64)*8]);
      GLL(B + (n0 + rowS[c])*(size_t)BST + k0 + chS[c]*8, &Bs[buf][(c*256 + wave*64)*8]);
    }
  };

  STAGE(0, 0);
#pragma unroll 2
  for (int ks = 0; ks < KSTEPS; ++ks) {
    int cur = ks & 1;
    if (ks + 1 < KSTEPS) {
      STAGE(cur ^ 1, ks + 1);
      asm volatile("s_waitcnt vmcnt(4)" ::: "memory");
    } else {
      asm volatile("s_waitcnt vmcnt(0)" ::: "memory");
    }
    __builtin_amdgcn_s_barrier();
    __builtin_amdgcn_sched_barrier(0);
    half8 a[4], bb[4];
    const f16* Af = &As[cur][(wm*64 + l15)*32 + pc];
    const f16* Bf = &Bs[cur][(wn*64 + l15)*32 + pc];
#pragma unroll
    for (int mi=0;mi<4;++mi) a[mi]  = *(const half8*)(Af + mi*16*32);
#pragma unroll
    for (int ni=0;ni<4;++ni) bb[ni] = *(const half8*)(Bf + ni*16*32);
    __builtin_amdgcn_s_setprio(1);
#pragma unroll
    for (int mi=0;mi<4;++mi)
#pragma unroll
      for (int ni=0;ni<4;++ni)
        acc[mi][ni] = __builtin_amdgcn_mfma_f32_16x16x32_f16(a[mi], bb[ni], acc[mi][ni], 0,0,0);
    __builtin_amdgcn_s_setprio(0);
    __builtin_amdgcn_sched_barrier(0);
    __builtin_amdgcn_s_barrier();
  }
  float cscale = SCALEQ ? SCALE : 1.0f;
#pragma unroll
  for (int mi=0;mi<4;++mi)
#pragma unroll
    for (int ni=0;ni<4;++ni)
#pragma unroll
      for (int j=0;j<4;++j) {
        size_t row = m0 + wm*64 + mi*16 + 4*l4 + j;
        size_t col = n0 + wn*64 + ni*16 + l15;
        C[row*CST + col] = (f16)(acc[mi][ni][j] * cscale);
      }
}

// ---------------- qk: q[b][h*64+d] = x_center @ Wq slice (f32); grid (64 b, 8 h) ----
__global__ __launch_bounds__(256) void qk(const float* __restrict__ x, const float* __restrict__ Wq,
                                          float* __restrict__ qbuf) {
  int b = blockIdx.x, h = blockIdx.y;
  int t = threadIdx.x;
  __shared__ float xc[1024];
  __shared__ float part[4][64];
  const float* xcg = x + ((size_t)b*256 + 128)*1024;
#pragma unroll
  for (int i = 0; i < 4; ++i) xc[t + 256*i] = xcg[t + 256*i];
  __syncthreads();
  int d = t & 63, chunk = t >> 6;
  float s = 0.f;
  const float* wq = Wq + (size_t)(chunk*256)*512 + h*64 + d;
#pragma unroll 8
  for (int c = 0; c < 256; ++c) s += xc[chunk*256 + c] * wq[(size_t)c*512];
  part[chunk][d] = s;
  __syncthreads();
  if (t < 64) qbuf[(size_t)b*512 + h*64 + t] = part[0][t]+part[1][t]+part[2][t]+part[3][t];
}

// ---------------- uk: u16[b][h][d] = sum_j Wkv[d][h*64+j] * q[b][h][j]; also zeroes pad rows ----
__global__ __launch_bounds__(256) void uk(const float* __restrict__ Wkv, const float* __restrict__ qbuf,
                                          f16* __restrict__ u16) {
  int h = blockIdx.x, dc = blockIdx.y;
  int t = threadIdx.x;
  __shared__ float Wk[32][64];
  __shared__ float qT[64][65];
  {
    int j = t & 63, g = t >> 6;
#pragma unroll
    for (int rr = 0; rr < 8; ++rr) {
      int dd = g*8 + rr;
      Wk[dd][j] = Wkv[(size_t)(dc*32 + dd)*1024 + h*64 + j];
    }
#pragma unroll
    for (int rr = 0; rr < 16; ++rr) {
      int bb = g*16 + rr;
      qT[j][bb] = qbuf[(size_t)bb*512 + h*64 + j];
    }
  }
  __syncthreads();
  int b = t & 63, dq = t >> 6;
#pragma unroll
  for (int i = 0; i < 8; ++i) {
    int dd = dq*8 + i;
    float s = 0.f;
#pragma unroll 8
    for (int j = 0; j < 64; ++j) s += qT[j][b] * Wk[dd][j];
    u16[((size_t)b*16 + h)*1024 + dc*32 + dd]       = (f16)s;
    u16[((size_t)b*16 + 8 + h)*1024 + dc*32 + dd]   = (f16)0.f;   // zero-pad row (replaces memset)
  }
}

// ---------------- lgk: logits[b][n][h] = sum_d x[b][n][d] * u16[b][h][d] (MFMA, 1 wave) ----
__global__ __launch_bounds__(64) void lgk(const float* __restrict__ x, const f16* __restrict__ u16,
                                          float* __restrict__ logitbuf) {
  int mt = blockIdx.x, b = blockIdx.y;
  int lane = threadIdx.x, l15 = lane & 15, l4 = lane >> 4;
  const float* Ap = x + ((size_t)b*256 + mt*16 + l15)*1024 + 8*l4;
  const f16* Bp = u16 + ((size_t)b*16 + l15)*1024 + 8*l4;
  f32x4 acc = (f32x4){0.f,0.f,0.f,0.f};
#pragma unroll 8
  for (int ks = 0; ks < 32; ++ks) {
    f32x4 lo = *(const f32x4*)(Ap + ks*32);
    f32x4 hi = *(const f32x4*)(Ap + ks*32 + 4);
    half8 h;
    h[0]=(f16)lo[0]; h[1]=(f16)lo[1]; h[2]=(f16)lo[2]; h[3]=(f16)lo[3];
    h[4]=(f16)hi[0]; h[5]=(f16)hi[1]; h[6]=(f16)hi[2]; h[7]=(f16)hi[3];
    acc = __builtin_amdgcn_mfma_f32_16x16x32_f16(h, *(const half8*)(Bp + ks*32), acc, 0,0,0);
  }
  if (l15 < 8) {
#pragma unroll
    for (int j = 0; j < 4; ++j)
      logitbuf[((size_t)b*256 + mt*16 + 4*l4 + j)*8 + l15] = acc[j];
  }
}

// ---------------- sm: softmax over n per (b,h); writes attnW f16 [b][16][256] (h>=8 zero) ----
__global__ __launch_bounds__(256) void sm(const float* __restrict__ logitbuf, f16* __restrict__ attnW) {
  int b = blockIdx.x, t = threadIdx.x;
  __shared__ float eL[256][9];
  __shared__ float Zs[8];
  float e[8];
  const float* lp = logitbuf + (size_t)b*256*8 + (size_t)t*8;
#pragma unroll
  for (int h = 0; h < 8; ++h) { e[h] = __expf(lp[h] * SCALE); eL[t][h] = e[h]; }
  __syncthreads();
  {
    int h = t >> 5, i = t & 31;
    float s = 0.f;
#pragma unroll
    for (int k = 0; k < 8; ++k) s += eL[i + 32*k][h];
#pragma unroll
    for (int o = 1; o < 32; o <<= 1) s += __shfl_xor(s, o);
    if (i == 0) Zs[h] = s;
  }
  __syncthreads();
#pragma unroll
  for (int h = 0; h < 8; ++h) attnW[((size_t)b*16 + h)*256 + t] = (f16)(e[h] / Zs[h]);
#pragma unroll
  for (int h = 8; h < 16; ++h) attnW[((size_t)b*16 + h)*256 + t] = (f16)0.f;
}

// ---------------- xbk: xbar[b][h][d] = sum_n attnW[b][h][n] * x[b][n][d] via xT (MFMA, 1 wave) ----
__global__ __launch_bounds__(64) void xbk(const f16* __restrict__ attnW, const f16* __restrict__ xT,
                                          f16* __restrict__ xbar) {
  int dt = blockIdx.x, b = blockIdx.y;
  int lane = threadIdx.x, l15 = lane & 15, l4 = lane >> 4;
  const f16* Ap = attnW + ((size_t)b*16 + l15)*256 + 8*l4;
  const f16* Bp = xT + ((size_t)b*1024 + dt*16 + l15)*256 + 8*l4;
  f32x4 acc = (f32x4){0.f,0.f,0.f,0.f};
#pragma unroll
  for (int ks = 0; ks < 8; ++ks)
    acc = __builtin_amdgcn_mfma_f32_16x16x32_f16(*(const half8*)(Ap + ks*32),
                                                 *(const half8*)(Bp + ks*32), acc, 0,0,0);
  if (l4 < 2) {
#pragma unroll
    for (int j = 0; j < 4; ++j)
      xbar[((size_t)b*8 + 4*l4 + j)*1024 + dt*16 + l15] = (f16)acc[j];
  }
}

// ---------------- vk: attnout[b][h*64+j] += sum_d xbar[b][h][d] * Wkv[d][512+h*64+j] ----
__global__ __launch_bounds__(256) void vk(const f16* __restrict__ xbar, const float* __restrict__ Wkv,
                                          float* __restrict__ attnout) {
  int h = blockIdx.x, dc = blockIdx.y, bc = blockIdx.z;
  int t = threadIdx.x;
  __shared__ float Wv[256][64];
  {
    int j = t & 63, g = t >> 6;
#pragma unroll
    for (int rr = 0; rr < 64; ++rr) {
      int dd = g*64 + rr;
      Wv[dd][j] = Wkv[(size_t)(dc*256 + dd)*1024 + 512 + h*64 + j];
    }
  }
  __syncthreads();
  int j = t & 63, bq = t >> 6;
  float s[4] = {0.f,0.f,0.f,0.f};
  const f16* xp[4];
#pragma unroll
  for (int bl = 0; bl < 4; ++bl)
    xp[bl] = xbar + ((size_t)(bc*16 + bq*4 + bl)*8 + h)*1024 + dc*256;
  for (int d8 = 0; d8 < 32; ++d8) {
    half8 xv[4];
#pragma unroll
    for (int bl = 0; bl < 4; ++bl) xv[bl] = *(const half8*)(xp[bl] + d8*8);
#pragma unroll
    for (int i = 0; i < 8; ++i) {
      float w = Wv[d8*8 + i][j];
#pragma unroll
      for (int bl = 0; bl < 4; ++bl) s[bl] += (float)xv[bl][i] * w;
    }
  }
#pragma unroll
  for (int bl = 0; bl < 4; ++bl)
    atomicAdd(&attnout[(size_t)(bc*16 + bq*4 + bl)*512 + h*64 + j], s[bl]);
}

// ---------------- spatialf: fused spatial = attnout @ Wout + bout; grid (4 ec, 64 b) ----
__global__ __launch_bounds__(256) void spatialf(const float* __restrict__ attnout, const float* __restrict__ Wout,
                                                const float* __restrict__ bout, float* __restrict__ spatial) {
  int ec = blockIdx.x, b = blockIdx.y;
  int t = threadIdx.x;
  __shared__ float ao[512];
  ao[t]       = attnout[(size_t)b*512 + t];
  ao[t + 256] = attnout[(size_t)b*512 + 256 + t];
  __syncthreads();
  int e = ec*256 + t;
  float a0 = bout[e], a1 = 0.f;
#pragma unroll 8
  for (int i = 0; i < 512; i += 2) {
    a0 += ao[i]     * Wout[(size_t)i*1024 + e];
    a1 += ao[i + 1] * Wout[(size_t)(i + 1)*1024 + e];
  }
  spatial[(size_t)b*1024 + e] = a0 + a1;
}

// ---------------- spec v12: Y-GEMM FUSED into prologue. 16 free-running waves at 4/SIMD.
// Stage xT[i0:64] into As (GLL, swizzled); compute Y = xT@MT^T*SCALE in-register (MT direct
// from L2); overwrite As with Y (swizzled ds_write); then v11's barrier-free K-loop.
__global__ __launch_bounds__(1024, 4) void speck(const f16* __restrict__ MT, const f16* __restrict__ xT,
                                                 const float* __restrict__ spatial, float* __restrict__ r) {
  __shared__ __attribute__((aligned(16))) char smem[163840];
  f16* As = (f16*)smem;                       // 32 KB: [64 r][32 slot16], slot swizzled by row&7
  f16* Bs = (f16*)(smem + 32768);             // 128 KB: [16 wave][2 slot][64 r][4 chunk][8 f16]
  float* sz   = (float*)smem;                 // post-loop alias of As (fenced by syncthreads)
  float* zfin = (float*)(smem + 4096);
  int bid = blockIdx.x;
  int xcd = bid & 7, q = bid >> 3;
  int b = xcd*8 + (q >> 4);                   // batch pinned to one XCD
  int iblk = q & 15;
  int t = threadIdx.x, lane = t & 63, wave = t >> 6;
  int l15 = lane & 15, l4 = lane >> 4;
  const f16* xTb = xT + (size_t)b*262144;
  int i0 = iblk*64;

  // ---- stage xT i-rows into As (2 GLL/wave, 3-bit row XOR on SOURCE slot) ----
#pragma unroll
  for (int g = 0; g < 2; ++g) {
    int u = (wave*2 + g)*64 + lane;           // linear 16B-slot index (write side)
    int rA = u >> 5, v = u & 31;
    int s = v ^ (rA & 7);                     // logical slot whose data lands at phys v
    GLL(xTb + (size_t)(i0 + rA)*256 + (s >> 2)*32 + (s & 3)*8, As + ((wave*2 + g)*64)*8);
  }
  // ---- per-wave private B stage: wave's 64 e-rows x 32 k -> 4 GLL ----
  auto STAGE_B = [&](int slot, int ks) {
    int k0 = ks*32;
#pragma unroll
    for (int c = 0; c < 4; ++c) {
      int u2 = c*64 + lane;
      int row = u2 >> 2, pchk = u2 & 3;
      int ch = pchk ^ (((row & 15) >> 1) & 3);
      GLL(xTb + (size_t)(wave*64 + row)*256 + k0 + ch*8,
          Bs + ((wave*2 + slot)*256 + c*64)*8);
    }
  };
  STAGE_B(0, 0);
  STAGE_B(1, 1);
  asm volatile("s_waitcnt vmcnt(8)" ::: "memory");   // own A-GLLs landed (B0,B1 in flight)
  __builtin_amdgcn_s_barrier();                      // all waves' xT-tile visible in As

  // ---- Y-compute: wave (w&3) owns rows (w&3)*16.., (w>>2) owns cols (w>>2)*64.. ----
  int r0 = (wave & 3)*16, c0 = (wave >> 2)*64;
  f32x4 accy[4];
#pragma unroll
  for (int ci = 0; ci < 4; ++ci) accy[ci] = (f32x4){0.f,0.f,0.f,0.f};
  int axor = l15 & 7;
#pragma unroll
  for (int ks = 0; ks < 8; ++ks) {
    int physA = ((ks*4 + l4) ^ axor)*8;
    half8 ax = *(const half8*)(As + (r0 + l15)*256 + physA);
#pragma unroll
    for (int ci = 0; ci < 4; ++ci) {
      half8 bmt = *(const half8*)(MT + (size_t)(c0 + ci*16 + l15)*256 + ks*32 + 8*l4);
      accy[ci] = __builtin_amdgcn_mfma_f32_16x16x32_f16(ax, bmt, accy[ci], 0,0,0);
    }
  }
  __syncthreads();                                   // all waves done READING xT from As
  // ---- write Y (f16, *SCALE) back into As with the same 3-bit swizzle ----
#pragma unroll
  for (int ci = 0; ci < 4; ++ci) {
    int col = c0 + ci*16 + l15;
    int ls = col >> 3, off = col & 7;
#pragma unroll
    for (int jj = 0; jj < 4; ++jj) {
      int row = r0 + 4*l4 + jj;
      As[row*256 + ((ls ^ (row & 7))*8) + off] = (f16)(accy[ci][jj] * SCALE);
    }
  }
  __syncthreads();                                   // Y visible to all waves

  f32x4 acc[4][4];
#pragma unroll
  for (int mi=0;mi<4;++mi)
#pragma unroll
    for (int ni=0;ni<4;++ni) acc[mi][ni] = (f32x4){0.f,0.f,0.f,0.f};
  int pc = (l4 ^ ((l15 >> 1) & 3)) * 8;

  // ---- barrier-free K-loop (v11): per-wave counted vmcnt; private B dbuf ----
#pragma unroll
  for (int ks = 0; ks < 8; ++ks) {
    int slot = ks & 1;
    if (ks < 7) asm volatile("s_waitcnt vmcnt(4)" ::: "memory");  // B(ks) landed, B(ks+1) in flight
    else        asm volatile("s_waitcnt vmcnt(0)" ::: "memory");
    __builtin_amdgcn_sched_barrier(0);
    half8 a[4], bb[4];
    const f16* Bbase = Bs + (wave*2 + slot)*2048;
    int physA = ((ks*4 + l4) ^ axor)*8;
#pragma unroll
    for (int mi = 0; mi < 4; ++mi) a[mi]  = *(const half8*)(As + (mi*16 + l15)*256 + physA);
#pragma unroll
    for (int ni = 0; ni < 4; ++ni) bb[ni] = *(const half8*)(Bbase + (ni*16 + l15)*32 + pc);
    asm volatile("s_waitcnt lgkmcnt(0)" ::: "memory");   // frags in regs -> slot reusable
    __builtin_amdgcn_sched_barrier(0);
    if (ks < 6) STAGE_B(slot, ks + 2);
    __builtin_amdgcn_s_setprio(1);
#pragma unroll
    for (int ni = 0; ni < 4; ++ni)
#pragma unroll
      for (int mi = 0; mi < 4; ++mi)
        acc[mi][ni] = __builtin_amdgcn_mfma_f32_16x16x32_f16(a[mi], bb[ni], acc[mi][ni], 0,0,0);
    __builtin_amdgcn_s_setprio(0);
    __builtin_amdgcn_sched_barrier(0);
  }
  // ---- no-max softmax (f32-safe): exp in place; wave-local row partials in regs ----
  float zr[4][4];
#pragma unroll
  for (int mi=0;mi<4;++mi)
#pragma unroll
    for (int jj=0;jj<4;++jj) {
      float s = 0.f;
#pragma unroll
      for (int ni=0;ni<4;++ni) {
        float e = __expf(acc[mi][ni][jj]);
        acc[mi][ni][jj] = e;
        s += e;
      }
#pragma unroll
      for (int o=1;o<16;o<<=1) s += __shfl_xor(s, o);
      zr[mi][jj] = s;
    }
  __syncthreads();                                   // all waves done with As -> alias as sz
  if (l15 == 0) {
#pragma unroll
    for (int mi=0;mi<4;++mi)
#pragma unroll
      for (int jj=0;jj<4;++jj) sz[(mi*16 + 4*l4 + jj)*16 + wave] = zr[mi][jj];
  }
  __syncthreads();
  {
    float v = sz[t];                                 // t = row*16 + w
#pragma unroll
    for (int o=1;o<16;o<<=1) v += __shfl_xor(v, o);
    if ((t & 15) == 0) zfin[t >> 4] = v;
  }
  __syncthreads();
  float f[4][4];
#pragma unroll
  for (int mi=0;mi<4;++mi)
#pragma unroll
    for (int jj=0;jj<4;++jj) {
      int row = mi*16 + 4*l4 + jj;
      f[mi][jj] = spatial[(size_t)b*1024 + i0 + row] / zfin[row];
    }
  float* rb = r + (size_t)b*1024;
#pragma unroll
  for (int ni=0;ni<4;++ni) {
    float v = 0.f;
#pragma unroll
    for (int mi=0;mi<4;++mi)
#pragma unroll
      for (int jj=0;jj<4;++jj) v += f[mi][jj]*acc[mi][ni][jj];
    v += __shfl_xor(v, 16);
    v += __shfl_xor(v, 32);
    if (l4 == 0) atomicAdd(rb + wave*64 + ni*16 + l15, v);
  }
}

// ---------------- broadcast: out[b,n,:] = r[b,:] ----------------
__global__ __launch_bounds__(256) void bcast(const float* __restrict__ r, float* __restrict__ out) {
  size_t row = blockIdx.x;
  int b = (int)(row >> 8);
  f32x4 v = *(const f32x4*)(r + (size_t)b*1024 + threadIdx.x*4);
  *(f32x4*)(out + row*1024 + (size_t)threadIdx.x*4) = v;
}

extern "C" void kernel_launch(void* const* d_in, const int* in_sizes, int n_in,
                              void* d_out, int out_size, void* d_ws, size_t ws_size,
                              hipStream_t stream) {
  const float* x     = (const float*)d_in[0];
  const float* Wq    = (const float*)d_in[1];
  const float* Wkv   = (const float*)d_in[2];
  const float* Wout  = (const float*)d_in[3];
  const float* bout  = (const float*)d_in[4];
  const float* Wspec = (const float*)d_in[5];
  float* out = (float*)d_out;
  char* ws = (char*)d_ws;
  // workspace aliases (stream-ordered):
  //   ws+0..6M:   u16pad@0, logitbuf@2M, attnW@2.5M, xbar@3M, qbuf@5.25M (attn chain scratch)
  //   ws+32M:     MT 128KB (mgemm -> speck); ws+64M: xT 32MB (prep_xT -> lgk/xbk/speck)
  //   ws+98M+:    Wspec16 / attnout / spatial / rvec
  f16*   u16pad   = (f16*)(ws);
  float* logitbuf = (float*)(ws + 2097152);
  f16*   attnW    = (f16*)(ws + 2621440);
  f16*   xbar     = (f16*)(ws + 3145728);
  float* qbuf     = (float*)(ws + 5242880);
  f16*   MT       = (f16*)(ws + 33554432);
  f16*   xT       = (f16*)(ws + 67108864);
  f16*   Wspec16  = (f16*)(ws + 102760448);
  float* attnout  = (float*)(ws + 103022592);
  float* spatial  = (float*)(ws + 103153664);
  float* rvec     = (float*)(ws + 103415808);
  (void)in_sizes; (void)n_in; (void)out_size; (void)ws_size;

  prep_xT     <<<dim3(32, 8, 64), dim3(256), 0, stream>>>(x, xT);
  prep_Wspec16<<<dim3(256),       dim3(256), 0, stream>>>(Wspec, Wspec16);
  // MT[m][n] = sum_j Wk[m][j]*Wq[n][j]  (256x256)
  gemm128<8,512,512,256,false><<<dim3(2, 2, 1), dim3(256), 0, stream>>>(Wspec16 + 256, Wspec16, MT, 0, 0, 0);
  hipMemsetAsync(attnout, 0, 64*512*sizeof(float), stream);
  qk          <<<dim3(64, 8),     dim3(256), 0, stream>>>(x, Wq, qbuf);
  uk          <<<dim3(8, 32),     dim3(256), 0, stream>>>(Wkv, qbuf, u16pad);
  lgk         <<<dim3(16, 64),    dim3(64),  0, stream>>>(x, u16pad, logitbuf);
  sm          <<<dim3(64),        dim3(256), 0, stream>>>(logitbuf, attnW);
  xbk         <<<dim3(64, 64),    dim3(64),  0, stream>>>(attnW, xT, xbar);
  vk          <<<dim3(8, 4, 4),   dim3(256), 0, stream>>>(xbar, Wkv, attnout);
  spatialf    <<<dim3(4, 64),     dim3(256), 0, stream>>>(attnout, Wout, bout, spatial);
  hipMemsetAsync(rvec, 0, 64*1024*sizeof(float), stream);
  speck       <<<dim3(1024),      dim3(1024), 0, stream>>>(MT, xT, spatial, rvec);
  bcast       <<<dim3(16384),     dim3(256), 0, stream>>>(rvec, out);
}

// Round 16
// 242.347 us; speedup vs baseline: 1.0417x; 1.0417x over previous
//
#include <hip/hip_runtime.h>
#include <hip/hip_bf16.h>
#include <cstdint>

typedef _Float16 f16;
typedef _Float16 half8 __attribute__((ext_vector_type(8)));
typedef float f32x4 __attribute__((ext_vector_type(4)));
typedef float f32x16 __attribute__((ext_vector_type(16)));

#define SCALE 0.125f

// async global->LDS, 16B per lane, dest = wave-uniform base + lane*16
#define GLL(src, dst) __builtin_amdgcn_global_load_lds( \
    (const __attribute__((address_space(1))) unsigned int*)(src), \
    (__attribute__((address_space(3))) unsigned int*)(dst), 16, 0, 0)

// ---------------- prep: x (64,256,1024) f32 -> xT (64,1024,256) f16 ----------------
__global__ __launch_bounds__(256) void prep_xT(const float* __restrict__ x, f16* __restrict__ xT) {
  __shared__ f16 tile[32][33];
  int b = blockIdx.z, nt = blockIdx.y, dt = blockIdx.x;
  int c = threadIdx.x & 31, rp = threadIdx.x >> 5;
  const float* xb = x + ((size_t)b*256 + nt*32)*1024 + dt*32;
#pragma unroll
  for (int p = 0; p < 4; ++p) { int r = p*8 + rp; tile[r][c] = (f16)xb[(size_t)r*1024 + c]; }
  __syncthreads();
  f16* o = xT + ((size_t)b*1024 + dt*32)*256 + nt*32;
#pragma unroll
  for (int p = 0; p < 4; ++p) { int r = p*8 + rp; o[(size_t)r*256 + c] = tile[c][r]; }
}

// ---------------- prep: Wspec (256,768) f32 -> Wspec16 [256][512] f16 (first 512 cols) ----
__global__ __launch_bounds__(256) void prep_Wspec16(const float* __restrict__ W, f16* __restrict__ Wt) {
  int row = blockIdx.x, t = threadIdx.x;
  Wt[(size_t)row*512 + t]       = (f16)W[(size_t)row*768 + t];
  Wt[(size_t)row*512 + 256 + t] = (f16)W[(size_t)row*768 + 256 + t];
}

// ---------------- 128x128x(32*KSTEPS) f16 GEMM, double-buffered + counted vmcnt ----
template<int KSTEPS, int AST, int BST, int CST, bool SCALEQ>
__global__ __launch_bounds__(256) void gemm128(const f16* __restrict__ Ag, const f16* __restrict__ Bg,
                                               f16* __restrict__ Cg, size_t aB, size_t bB, size_t cB) {
  __shared__ f16 As[2][128*32];
  __shared__ f16 Bs[2][128*32];
  const f16* A = Ag + (size_t)blockIdx.z*aB;
  const f16* B = Bg + (size_t)blockIdx.z*bB;
  f16* C = Cg + (size_t)blockIdx.z*cB;
  int t = threadIdx.x, lane = t & 63, wave = t >> 6;
  int l15 = lane & 15, l4 = lane >> 4;
  int wm = wave & 1, wn = wave >> 1;
  size_t m0 = (size_t)blockIdx.x*128, n0 = (size_t)blockIdx.y*128;
  f32x4 acc[4][4];
#pragma unroll
  for (int i=0;i<4;++i)
#pragma unroll
    for (int j=0;j<4;++j) acc[i][j] = (f32x4){0.f,0.f,0.f,0.f};
  int rowS[2], chS[2];
#pragma unroll
  for (int c=0;c<2;++c) {
    int slot = c*256 + t;
    rowS[c] = slot >> 2;
    chS[c]  = (slot & 3) ^ ((slot >> 3) & 3);
  }
  int pc = (l4 ^ ((l15 >> 1) & 3)) * 8;

  auto STAGE = [&](int buf, int ks) {
    int k0 = ks*32;
#pragma unroll
    for (int c=0;c<2;++c) {
      GLL(A + (m0 + rowS[c])*(size_t)AST + k0 + chS[c]*8, &As[buf][(c*256 + wave*64)*8]);
      GLL(B + (n0 + rowS[c])*(size_t)BST + k0 + chS[c]*8, &Bs[buf][(c*256 + wave*64)*8]);
    }
  };

  STAGE(0, 0);
#pragma unroll 2
  for (int ks = 0; ks < KSTEPS; ++ks) {
    int cur = ks & 1;
    if (ks + 1 < KSTEPS) {
      STAGE(cur ^ 1, ks + 1);
      asm volatile("s_waitcnt vmcnt(4)" ::: "memory");
    } else {
      asm volatile("s_waitcnt vmcnt(0)" ::: "memory");
    }
    __builtin_amdgcn_s_barrier();
    __builtin_amdgcn_sched_barrier(0);
    half8 a[4], bb[4];
    const f16* Af = &As[cur][(wm*64 + l15)*32 + pc];
    const f16* Bf = &Bs[cur][(wn*64 + l15)*32 + pc];
#pragma unroll
    for (int mi=0;mi<4;++mi) a[mi]  = *(const half8*)(Af + mi*16*32);
#pragma unroll
    for (int ni=0;ni<4;++ni) bb[ni] = *(const half8*)(Bf + ni*16*32);
    __builtin_amdgcn_s_setprio(1);
#pragma unroll
    for (int mi=0;mi<4;++mi)
#pragma unroll
      for (int ni=0;ni<4;++ni)
        acc[mi][ni] = __builtin_amdgcn_mfma_f32_16x16x32_f16(a[mi], bb[ni], acc[mi][ni], 0,0,0);
    __builtin_amdgcn_s_setprio(0);
    __builtin_amdgcn_sched_barrier(0);
    __builtin_amdgcn_s_barrier();
  }
  float cscale = SCALEQ ? SCALE : 1.0f;
#pragma unroll
  for (int mi=0;mi<4;++mi)
#pragma unroll
    for (int ni=0;ni<4;++ni)
#pragma unroll
      for (int j=0;j<4;++j) {
        size_t row = m0 + wm*64 + mi*16 + 4*l4 + j;
        size_t col = n0 + wn*64 + ni*16 + l15;
        C[row*CST + col] = (f16)(acc[mi][ni][j] * cscale);
      }
}

// ---------------- qk: q[b][h*64+d] = x_center @ Wq slice (f32); grid (64 b, 8 h) ----
__global__ __launch_bounds__(256) void qk(const float* __restrict__ x, const float* __restrict__ Wq,
                                          float* __restrict__ qbuf) {
  int b = blockIdx.x, h = blockIdx.y;
  int t = threadIdx.x;
  __shared__ float xc[1024];
  __shared__ float part[4][64];
  const float* xcg = x + ((size_t)b*256 + 128)*1024;
#pragma unroll
  for (int i = 0; i < 4; ++i) xc[t + 256*i] = xcg[t + 256*i];
  __syncthreads();
  int d = t & 63, chunk = t >> 6;
  float s = 0.f;
  const float* wq = Wq + (size_t)(chunk*256)*512 + h*64 + d;
#pragma unroll 8
  for (int c = 0; c < 256; ++c) s += xc[chunk*256 + c] * wq[(size_t)c*512];
  part[chunk][d] = s;
  __syncthreads();
  if (t < 64) qbuf[(size_t)b*512 + h*64 + t] = part[0][t]+part[1][t]+part[2][t]+part[3][t];
}

// ---------------- uk: u16[b][h][d] = sum_j Wkv[d][h*64+j] * q[b][h][j]; also zeroes pad rows ----
__global__ __launch_bounds__(256) void uk(const float* __restrict__ Wkv, const float* __restrict__ qbuf,
                                          f16* __restrict__ u16) {
  int h = blockIdx.x, dc = blockIdx.y;
  int t = threadIdx.x;
  __shared__ float Wk[32][64];
  __shared__ float qT[64][65];
  {
    int j = t & 63, g = t >> 6;
#pragma unroll
    for (int rr = 0; rr < 8; ++rr) {
      int dd = g*8 + rr;
      Wk[dd][j] = Wkv[(size_t)(dc*32 + dd)*1024 + h*64 + j];
    }
#pragma unroll
    for (int rr = 0; rr < 16; ++rr) {
      int bb = g*16 + rr;
      qT[j][bb] = qbuf[(size_t)bb*512 + h*64 + j];
    }
  }
  __syncthreads();
  int b = t & 63, dq = t >> 6;
#pragma unroll
  for (int i = 0; i < 8; ++i) {
    int dd = dq*8 + i;
    float s = 0.f;
#pragma unroll 8
    for (int j = 0; j < 64; ++j) s += qT[j][b] * Wk[dd][j];
    u16[((size_t)b*16 + h)*1024 + dc*32 + dd]       = (f16)s;
    u16[((size_t)b*16 + 8 + h)*1024 + dc*32 + dd]   = (f16)0.f;   // zero-pad row (replaces memset)
  }
}

// ---------------- lgk: logits[b][n][h] = sum_d x[b][n][d] * u16[b][h][d] (MFMA, 1 wave) ----
__global__ __launch_bounds__(64) void lgk(const float* __restrict__ x, const f16* __restrict__ u16,
                                          float* __restrict__ logitbuf) {
  int mt = blockIdx.x, b = blockIdx.y;
  int lane = threadIdx.x, l15 = lane & 15, l4 = lane >> 4;
  const float* Ap = x + ((size_t)b*256 + mt*16 + l15)*1024 + 8*l4;
  const f16* Bp = u16 + ((size_t)b*16 + l15)*1024 + 8*l4;
  f32x4 acc = (f32x4){0.f,0.f,0.f,0.f};
#pragma unroll 8
  for (int ks = 0; ks < 32; ++ks) {
    f32x4 lo = *(const f32x4*)(Ap + ks*32);
    f32x4 hi = *(const f32x4*)(Ap + ks*32 + 4);
    half8 h;
    h[0]=(f16)lo[0]; h[1]=(f16)lo[1]; h[2]=(f16)lo[2]; h[3]=(f16)lo[3];
    h[4]=(f16)hi[0]; h[5]=(f16)hi[1]; h[6]=(f16)hi[2]; h[7]=(f16)hi[3];
    acc = __builtin_amdgcn_mfma_f32_16x16x32_f16(h, *(const half8*)(Bp + ks*32), acc, 0,0,0);
  }
  if (l15 < 8) {
#pragma unroll
    for (int j = 0; j < 4; ++j)
      logitbuf[((size_t)b*256 + mt*16 + 4*l4 + j)*8 + l15] = acc[j];
  }
}

// ---------------- sm: softmax over n per (b,h); writes attnW f16 [b][16][256] (h>=8 zero) ----
__global__ __launch_bounds__(256) void sm(const float* __restrict__ logitbuf, f16* __restrict__ attnW) {
  int b = blockIdx.x, t = threadIdx.x;
  __shared__ float eL[256][9];
  __shared__ float Zs[8];
  float e[8];
  const float* lp = logitbuf + (size_t)b*256*8 + (size_t)t*8;
#pragma unroll
  for (int h = 0; h < 8; ++h) { e[h] = __expf(lp[h] * SCALE); eL[t][h] = e[h]; }
  __syncthreads();
  {
    int h = t >> 5, i = t & 31;
    float s = 0.f;
#pragma unroll
    for (int k = 0; k < 8; ++k) s += eL[i + 32*k][h];
#pragma unroll
    for (int o = 1; o < 32; o <<= 1) s += __shfl_xor(s, o);
    if (i == 0) Zs[h] = s;
  }
  __syncthreads();
#pragma unroll
  for (int h = 0; h < 8; ++h) attnW[((size_t)b*16 + h)*256 + t] = (f16)(e[h] / Zs[h]);
#pragma unroll
  for (int h = 8; h < 16; ++h) attnW[((size_t)b*16 + h)*256 + t] = (f16)0.f;
}

// ---------------- xbk: xbar[b][h][d] = sum_n attnW[b][h][n] * x[b][n][d] via xT (MFMA, 1 wave) ----
__global__ __launch_bounds__(64) void xbk(const f16* __restrict__ attnW, const f16* __restrict__ xT,
                                          f16* __restrict__ xbar) {
  int dt = blockIdx.x, b = blockIdx.y;
  int lane = threadIdx.x, l15 = lane & 15, l4 = lane >> 4;
  const f16* Ap = attnW + ((size_t)b*16 + l15)*256 + 8*l4;
  const f16* Bp = xT + ((size_t)b*1024 + dt*16 + l15)*256 + 8*l4;
  f32x4 acc = (f32x4){0.f,0.f,0.f,0.f};
#pragma unroll
  for (int ks = 0; ks < 8; ++ks)
    acc = __builtin_amdgcn_mfma_f32_16x16x32_f16(*(const half8*)(Ap + ks*32),
                                                 *(const half8*)(Bp + ks*32), acc, 0,0,0);
  if (l4 < 2) {
#pragma unroll
    for (int j = 0; j < 4; ++j)
      xbar[((size_t)b*8 + 4*l4 + j)*1024 + dt*16 + l15] = (f16)acc[j];
  }
}

// ---------------- vk: attnout[b][h*64+j] += sum_d xbar[b][h][d] * Wkv[d][512+h*64+j] ----
__global__ __launch_bounds__(256) void vk(const f16* __restrict__ xbar, const float* __restrict__ Wkv,
                                          float* __restrict__ attnout) {
  int h = blockIdx.x, dc = blockIdx.y, bc = blockIdx.z;
  int t = threadIdx.x;
  __shared__ float Wv[256][64];
  {
    int j = t & 63, g = t >> 6;
#pragma unroll
    for (int rr = 0; rr < 64; ++rr) {
      int dd = g*64 + rr;
      Wv[dd][j] = Wkv[(size_t)(dc*256 + dd)*1024 + 512 + h*64 + j];
    }
  }
  __syncthreads();
  int j = t & 63, bq = t >> 6;
  float s[4] = {0.f,0.f,0.f,0.f};
  const f16* xp[4];
#pragma unroll
  for (int bl = 0; bl < 4; ++bl)
    xp[bl] = xbar + ((size_t)(bc*16 + bq*4 + bl)*8 + h)*1024 + dc*256;
  for (int d8 = 0; d8 < 32; ++d8) {
    half8 xv[4];
#pragma unroll
    for (int bl = 0; bl < 4; ++bl) xv[bl] = *(const half8*)(xp[bl] + d8*8);
#pragma unroll
    for (int i = 0; i < 8; ++i) {
      float w = Wv[d8*8 + i][j];
#pragma unroll
      for (int bl = 0; bl < 4; ++bl) s[bl] += (float)xv[bl][i] * w;
    }
  }
#pragma unroll
  for (int bl = 0; bl < 4; ++bl)
    atomicAdd(&attnout[(size_t)(bc*16 + bq*4 + bl)*512 + h*64 + j], s[bl]);
}

// ---------------- spatialf: fused spatial = attnout @ Wout + bout; grid (4 ec, 64 b) ----
__global__ __launch_bounds__(256) void spatialf(const float* __restrict__ attnout, const float* __restrict__ Wout,
                                                const float* __restrict__ bout, float* __restrict__ spatial) {
  int ec = blockIdx.x, b = blockIdx.y;
  int t = threadIdx.x;
  __shared__ float ao[512];
  ao[t]       = attnout[(size_t)b*512 + t];
  ao[t + 256] = attnout[(size_t)b*512 + 256 + t];
  __syncthreads();
  int e = ec*256 + t;
  float a0 = bout[e], a1 = 0.f;
#pragma unroll 8
  for (int i = 0; i < 512; i += 2) {
    a0 += ao[i]     * Wout[(size_t)i*1024 + e];
    a1 += ao[i + 1] * Wout[(size_t)(i + 1)*1024 + e];
  }
  spatial[(size_t)b*1024 + e] = a0 + a1;
}

// ---------------- spec v13b: 32x32x16 K-loop (halves B LDS-reads) + RACE FIX: syncthreads
// after the free-running K-loop BEFORE sz writes (sz aliases As; v13's in-loop writes raced
// with slower waves' A-frag reads -> NaN). 16 waves at 4/SIMD; wave owns 64 e-rows.
__global__ __launch_bounds__(1024, 4) void speck(const f16* __restrict__ Y, const f16* __restrict__ xT,
                                                 const float* __restrict__ spatial, float* __restrict__ r) {
  __shared__ __attribute__((aligned(16))) char smem[163840];
  f16* As = (f16*)smem;                       // 32 KB: [64 r][32 slot16], slot swizzled by row&7
  f16* Bs = (f16*)(smem + 32768);             // 128 KB: [16 wave][2 slot][64 r][4 chunk][8 f16]
  float* sz   = (float*)smem;                 // post-loop alias of As (NOW barrier-fenced)
  float* zfin = (float*)(smem + 4096);
  int bid = blockIdx.x;
  int xcd = bid & 7, q = bid >> 3;
  int b = xcd*8 + (q >> 4);                   // batch pinned to one XCD
  int iblk = q & 15;
  int t = threadIdx.x, lane = t & 63, wave = t >> 6;
  int l31 = lane & 31, hi = lane >> 5;
  const f16* Yb  = Y  + (size_t)b*262144;
  const f16* xTb = xT + (size_t)b*262144;
  int i0 = iblk*64;

  f32x16 acc[2][2];
#pragma unroll
  for (int ti=0;ti<2;++ti)
#pragma unroll
    for (int tj=0;tj<2;++tj)
#pragma unroll
      for (int j=0;j<16;++j) acc[ti][tj][j] = 0.f;

  // ---- A stage: 64x256 Y tile, 2 GLL per wave; 3-bit row XOR on the SOURCE slot ----
#pragma unroll
  for (int g = 0; g < 2; ++g) {
    int u = (wave*2 + g)*64 + lane;           // linear 16B-slot index (write side)
    int rA = u >> 5, v = u & 31;
    int s = v ^ (rA & 7);                     // logical slot whose data lands at phys v
    GLL(Yb + (size_t)(i0 + rA)*256 + (s >> 2)*32 + (s & 3)*8, As + ((wave*2 + g)*64)*8);
  }
  // ---- per-wave private B stage: wave's 64 e-rows x 32 k -> 4 GLL (2-bit chunk XOR) ----
  auto STAGE_B = [&](int slot, int ks) {
    int k0 = ks*32;
#pragma unroll
    for (int c = 0; c < 4; ++c) {
      int u2 = c*64 + lane;
      int row = u2 >> 2, pchk = u2 & 3;
      int ch = pchk ^ (((row & 15) >> 1) & 3);
      GLL(xTb + (size_t)(wave*64 + row)*256 + k0 + ch*8,
          Bs + ((wave*2 + slot)*256 + c*64)*8);
    }
  };
  STAGE_B(0, 0);
  STAGE_B(1, 1);
  asm volatile("s_waitcnt vmcnt(8)" ::: "memory");   // own A landed (B0,B1 still in flight)
  __builtin_amdgcn_s_barrier();                      // all waves' A visible

  int axorA = l31 & 7;
  int bxor  = ((l31 & 15) >> 1) & 3;
#pragma unroll
  for (int ks = 0; ks < 8; ++ks) {
    int slot = ks & 1;
    if (ks < 7) asm volatile("s_waitcnt vmcnt(4)" ::: "memory");  // B(ks) landed, B(ks+1) in flight
    else        asm volatile("s_waitcnt vmcnt(0)" ::: "memory");
    __builtin_amdgcn_sched_barrier(0);
    half8 a[2][2], bb[2][2];
    const f16* Bbase = Bs + (wave*2 + slot)*2048;
#pragma unroll
    for (int ti = 0; ti < 2; ++ti)
#pragma unroll
      for (int kh = 0; kh < 2; ++kh) {
        int ls = ks*4 + kh*2 + hi;                   // logical 16B-slot (k = ls*8)
        a[ti][kh] = *(const half8*)(As + (ti*32 + l31)*256 + ((ls ^ axorA)*8));
      }
#pragma unroll
    for (int tj = 0; tj < 2; ++tj)
#pragma unroll
      for (int kh = 0; kh < 2; ++kh) {
        int lc = kh*2 + hi;                          // logical chunk within kstep
        bb[tj][kh] = *(const half8*)(Bbase + (tj*32 + l31)*32 + ((lc ^ bxor)*8));
      }
    asm volatile("s_waitcnt lgkmcnt(0)" ::: "memory");   // frags in regs -> slot reusable
    __builtin_amdgcn_sched_barrier(0);
    if (ks < 6) STAGE_B(slot, ks + 2);
    __builtin_amdgcn_s_setprio(1);
#pragma unroll
    for (int tj = 0; tj < 2; ++tj)
#pragma unroll
      for (int ti = 0; ti < 2; ++ti)
#pragma unroll
        for (int kh = 0; kh < 2; ++kh)
          acc[ti][tj] = __builtin_amdgcn_mfma_f32_32x32x16_f16(a[ti][kh], bb[tj][kh], acc[ti][tj], 0,0,0);
    __builtin_amdgcn_s_setprio(0);
    __builtin_amdgcn_sched_barrier(0);
  }
  __syncthreads();   // RACE FIX: all waves finished reading As before sz (alias) is written

  // ---- no-max softmax (f32-safe): exp in place; row sums over wave's 64 cols ----
  // lane's rows: ti*32 + (reg&3) + 8*(reg>>2) + 4*hi ; cols: wave*64 + tj*32 + l31
#pragma unroll
  for (int ti = 0; ti < 2; ++ti)
#pragma unroll
    for (int reg = 0; reg < 16; ++reg) {
      float e0 = __expf(acc[ti][0][reg]); acc[ti][0][reg] = e0;
      float e1 = __expf(acc[ti][1][reg]); acc[ti][1][reg] = e1;
      float s = e0 + e1;
#pragma unroll
      for (int o = 1; o < 32; o <<= 1) s += __shfl_xor(s, o);
      if (l31 == 0) {
        int row = ti*32 + (reg & 3) + 8*(reg >> 2) + 4*hi;
        sz[row*16 + wave] = s;
      }
    }
  __syncthreads();
  {
    float v = sz[t];                                 // t = row*16 + w
#pragma unroll
    for (int o = 1; o < 16; o <<= 1) v += __shfl_xor(v, o);
    if ((t & 15) == 0) zfin[t >> 4] = v;
  }
  __syncthreads();
  const float* spb = spatial + (size_t)b*1024 + i0;
  float* rb = r + (size_t)b*1024;
  float v0 = 0.f, v1 = 0.f;
#pragma unroll
  for (int ti = 0; ti < 2; ++ti)
#pragma unroll
    for (int reg = 0; reg < 16; ++reg) {
      int row = ti*32 + (reg & 3) + 8*(reg >> 2) + 4*hi;
      float g = spb[row] / zfin[row];
      v0 += g * acc[ti][0][reg];
      v1 += g * acc[ti][1][reg];
    }
  v0 += __shfl_xor(v0, 32);
  v1 += __shfl_xor(v1, 32);
  if (lane < 32) {
    atomicAdd(rb + wave*64 + l31, v0);
    atomicAdd(rb + wave*64 + 32 + l31, v1);
  }
}

// ---------------- broadcast: out[b,n,:] = r[b,:] ----------------
__global__ __launch_bounds__(256) void bcast(const float* __restrict__ r, float* __restrict__ out) {
  size_t row = blockIdx.x;
  int b = (int)(row >> 8);
  f32x4 v = *(const f32x4*)(r + (size_t)b*1024 + threadIdx.x*4);
  *(f32x4*)(out + row*1024 + (size_t)threadIdx.x*4) = v;
}

extern "C" void kernel_launch(void* const* d_in, const int* in_sizes, int n_in,
                              void* d_out, int out_size, void* d_ws, size_t ws_size,
                              hipStream_t stream) {
  const float* x     = (const float*)d_in[0];
  const float* Wq    = (const float*)d_in[1];
  const float* Wkv   = (const float*)d_in[2];
  const float* Wout  = (const float*)d_in[3];
  const float* bout  = (const float*)d_in[4];
  const float* Wspec = (const float*)d_in[5];
  float* out = (float*)d_out;
  char* ws = (char*)d_ws;
  // workspace aliases (stream-ordered):
  //   ws+0..32M:  Y (gemm_qs -> speck). Aliases while Y dead: u16pad@0,
  //               logitbuf@2M, attnW@2.5M, xbar@3M, qbuf@5.25M
  //   ws+32M:     MT 128KB; ws+64M: xT 32MB; ws+98M+: Wspec16/attnout/spatial/rvec
  f16*   Ybuf     = (f16*)(ws);
  f16*   u16pad   = (f16*)(ws);
  float* logitbuf = (float*)(ws + 2097152);
  f16*   attnW    = (f16*)(ws + 2621440);
  f16*   xbar     = (f16*)(ws + 3145728);
  float* qbuf     = (float*)(ws + 5242880);
  f16*   MT       = (f16*)(ws + 33554432);
  f16*   xT       = (f16*)(ws + 67108864);
  f16*   Wspec16  = (f16*)(ws + 102760448);
  float* attnout  = (float*)(ws + 103022592);
  float* spatial  = (float*)(ws + 103153664);
  float* rvec     = (float*)(ws + 103415808);
  (void)in_sizes; (void)n_in; (void)out_size; (void)ws_size;

  prep_xT     <<<dim3(32, 8, 64), dim3(256), 0, stream>>>(x, xT);
  prep_Wspec16<<<dim3(256),       dim3(256), 0, stream>>>(Wspec, Wspec16);
  // MT[m][n] = sum_j Wk[m][j]*Wq[n][j]  (256x256)
  gemm128<8,512,512,256,false><<<dim3(2, 2, 1), dim3(256), 0, stream>>>(Wspec16 + 256, Wspec16, MT, 0, 0, 0);
  hipMemsetAsync(attnout, 0, 64*512*sizeof(float), stream);
  qk          <<<dim3(64, 8),     dim3(256), 0, stream>>>(x, Wq, qbuf);
  uk          <<<dim3(8, 32),     dim3(256), 0, stream>>>(Wkv, qbuf, u16pad);
  lgk         <<<dim3(16, 64),    dim3(64),  0, stream>>>(x, u16pad, logitbuf);
  sm          <<<dim3(64),        dim3(256), 0, stream>>>(logitbuf, attnW);
  xbk         <<<dim3(64, 64),    dim3(64),  0, stream>>>(attnW, xT, xbar);
  vk          <<<dim3(8, 4, 4),   dim3(256), 0, stream>>>(xbar, Wkv, attnout);
  spatialf    <<<dim3(4, 64),     dim3(256), 0, stream>>>(attnout, Wout, bout, spatial);
  // Y[b] = xT[b] @ MT^T * SCALE  (1024x256, K=256)
  gemm128<8,256,256,256,true><<<dim3(8, 2, 64), dim3(256), 0, stream>>>(xT, MT, Ybuf,
                                                                        262144, 0, 262144);
  hipMemsetAsync(rvec, 0, 64*1024*sizeof(float), stream);
  speck       <<<dim3(1024),      dim3(1024), 0, stream>>>(Ybuf, xT, spatial, rvec);
  bcast       <<<dim3(16384),     dim3(256), 0, stream>>>(rvec, out);
}

// Round 17
// 213.498 us; speedup vs baseline: 1.1824x; 1.1351x over previous
//
#include <hip/hip_runtime.h>
#include <hip/hip_bf16.h>
#include <cstdint>

typedef _Float16 f16;
typedef _Float16 half8 __attribute__((ext_vector_type(8)));
typedef float f32x4 __attribute__((ext_vector_type(4)));

#define SCALE 0.125f

// async global->LDS, 16B per lane, dest = wave-uniform base + lane*16
#define GLL(src, dst) __builtin_amdgcn_global_load_lds( \
    (const __attribute__((address_space(1))) unsigned int*)(src), \
    (__attribute__((address_space(3))) unsigned int*)(dst), 16, 0, 0)

// ---------------- prep: x (64,256,1024) f32 -> xT (64,1024,256) f16 (vectorized both sides) ----
__global__ __launch_bounds__(256) void prep_xT(const float* __restrict__ x, f16* __restrict__ xT) {
  __shared__ f16 tile[64][34];                 // 64 n x 32 d, pad 34 (17-bank stride)
  int dt = blockIdx.x, nt = blockIdx.y, b = blockIdx.z;
  int t = threadIdx.x;
#pragma unroll
  for (int p = 0; p < 2; ++p) {
    int n = p*32 + (t >> 3), dg = t & 7;
    f32x4 v = *(const f32x4*)(x + ((size_t)b*256 + nt*64 + n)*1024 + dt*32 + dg*4);
    f16* dst = &tile[n][dg*4];
    dst[0] = (f16)v[0]; dst[1] = (f16)v[1]; dst[2] = (f16)v[2]; dst[3] = (f16)v[3];
  }
  __syncthreads();
  {
    int d = t >> 3, ng = t & 7;
    half8 o;
#pragma unroll
    for (int j = 0; j < 8; ++j) o[j] = tile[ng*8 + j][d];
    *(half8*)(xT + ((size_t)b*1024 + dt*32 + d)*256 + nt*64 + ng*8) = o;
  }
}

// ---------------- prep: Wspec (256,768) f32 -> Wspec16 [256][512] f16 (first 512 cols) ----
__global__ __launch_bounds__(256) void prep_Wspec16(const float* __restrict__ W, f16* __restrict__ Wt) {
  int row = blockIdx.x, t = threadIdx.x;
  Wt[(size_t)row*512 + t]       = (f16)W[(size_t)row*768 + t];
  Wt[(size_t)row*512 + 256 + t] = (f16)W[(size_t)row*768 + 256 + t];
}

// ---------------- 128x128x(32*KSTEPS) f16 GEMM, double-buffered + counted vmcnt ----
template<int KSTEPS, int AST, int BST, int CST, bool SCALEQ>
__global__ __launch_bounds__(256) void gemm128(const f16* __restrict__ Ag, const f16* __restrict__ Bg,
                                               f16* __restrict__ Cg, size_t aB, size_t bB, size_t cB) {
  __shared__ f16 As[2][128*32];
  __shared__ f16 Bs[2][128*32];
  const f16* A = Ag + (size_t)blockIdx.z*aB;
  const f16* B = Bg + (size_t)blockIdx.z*bB;
  f16* C = Cg + (size_t)blockIdx.z*cB;
  int t = threadIdx.x, lane = t & 63, wave = t >> 6;
  int l15 = lane & 15, l4 = lane >> 4;
  int wm = wave & 1, wn = wave >> 1;
  size_t m0 = (size_t)blockIdx.x*128, n0 = (size_t)blockIdx.y*128;
  f32x4 acc[4][4];
#pragma unroll
  for (int i=0;i<4;++i)
#pragma unroll
    for (int j=0;j<4;++j) acc[i][j] = (f32x4){0.f,0.f,0.f,0.f};
  int rowS[2], chS[2];
#pragma unroll
  for (int c=0;c<2;++c) {
    int slot = c*256 + t;
    rowS[c] = slot >> 2;
    chS[c]  = (slot & 3) ^ ((slot >> 3) & 3);
  }
  int pc = (l4 ^ ((l15 >> 1) & 3)) * 8;

  auto STAGE = [&](int buf, int ks) {
    int k0 = ks*32;
#pragma unroll
    for (int c=0;c<2;++c) {
      GLL(A + (m0 + rowS[c])*(size_t)AST + k0 + chS[c]*8, &As[buf][(c*256 + wave*64)*8]);
      GLL(B + (n0 + rowS[c])*(size_t)BST + k0 + chS[c]*8, &Bs[buf][(c*256 + wave*64)*8]);
    }
  };

  STAGE(0, 0);
#pragma unroll 2
  for (int ks = 0; ks < KSTEPS; ++ks) {
    int cur = ks & 1;
    if (ks + 1 < KSTEPS) {
      STAGE(cur ^ 1, ks + 1);
      asm volatile("s_waitcnt vmcnt(4)" ::: "memory");
    } else {
      asm volatile("s_waitcnt vmcnt(0)" ::: "memory");
    }
    __builtin_amdgcn_s_barrier();
    __builtin_amdgcn_sched_barrier(0);
    half8 a[4], bb[4];
    const f16* Af = &As[cur][(wm*64 + l15)*32 + pc];
    const f16* Bf = &Bs[cur][(wn*64 + l15)*32 + pc];
#pragma unroll
    for (int mi=0;mi<4;++mi) a[mi]  = *(const half8*)(Af + mi*16*32);
#pragma unroll
    for (int ni=0;ni<4;++ni) bb[ni] = *(const half8*)(Bf + ni*16*32);
    __builtin_amdgcn_s_setprio(1);
#pragma unroll
    for (int mi=0;mi<4;++mi)
#pragma unroll
      for (int ni=0;ni<4;++ni)
        acc[mi][ni] = __builtin_amdgcn_mfma_f32_16x16x32_f16(a[mi], bb[ni], acc[mi][ni], 0,0,0);
    __builtin_amdgcn_s_setprio(0);
    __builtin_amdgcn_sched_barrier(0);
    __builtin_amdgcn_s_barrier();
  }
  float cscale = SCALEQ ? SCALE : 1.0f;
#pragma unroll
  for (int mi=0;mi<4;++mi)
#pragma unroll
    for (int ni=0;ni<4;++ni)
#pragma unroll
      for (int j=0;j<4;++j) {
        size_t row = m0 + wm*64 + mi*16 + 4*l4 + j;
        size_t col = n0 + wn*64 + ni*16 + l15;
        C[row*CST + col] = (f16)(acc[mi][ni][j] * cscale);
      }
}

// ---------------- qk: q[b][h*64+d] = x_center @ Wq slice (f32); grid (64 b, 8 h) ----
__global__ __launch_bounds__(256) void qk(const float* __restrict__ x, const float* __restrict__ Wq,
                                          float* __restrict__ qbuf) {
  int b = blockIdx.x, h = blockIdx.y;
  int t = threadIdx.x;
  __shared__ float xc[1024];
  __shared__ float part[4][64];
  const float* xcg = x + ((size_t)b*256 + 128)*1024;
#pragma unroll
  for (int i = 0; i < 4; ++i) xc[t + 256*i] = xcg[t + 256*i];
  __syncthreads();
  int d = t & 63, chunk = t >> 6;
  float s = 0.f;
  const float* wq = Wq + (size_t)(chunk*256)*512 + h*64 + d;
#pragma unroll 8
  for (int c = 0; c < 256; ++c) s += xc[chunk*256 + c] * wq[(size_t)c*512];
  part[chunk][d] = s;
  __syncthreads();
  if (t < 64) qbuf[(size_t)b*512 + h*64 + t] = part[0][t]+part[1][t]+part[2][t]+part[3][t];
}

// ---------------- uk: u16[b][h][d] = sum_j Wkv[d][h*64+j] * q[b][h][j]; also zeroes pad rows ----
__global__ __launch_bounds__(256) void uk(const float* __restrict__ Wkv, const float* __restrict__ qbuf,
                                          f16* __restrict__ u16) {
  int h = blockIdx.x, dc = blockIdx.y;
  int t = threadIdx.x;
  __shared__ float Wk[32][64];
  __shared__ float qT[64][65];
  {
    int j = t & 63, g = t >> 6;
#pragma unroll
    for (int rr = 0; rr < 8; ++rr) {
      int dd = g*8 + rr;
      Wk[dd][j] = Wkv[(size_t)(dc*32 + dd)*1024 + h*64 + j];
    }
#pragma unroll
    for (int rr = 0; rr < 16; ++rr) {
      int bb = g*16 + rr;
      qT[j][bb] = qbuf[(size_t)bb*512 + h*64 + j];
    }
  }
  __syncthreads();
  int b = t & 63, dq = t >> 6;
#pragma unroll
  for (int i = 0; i < 8; ++i) {
    int dd = dq*8 + i;
    float s = 0.f;
#pragma unroll 8
    for (int j = 0; j < 64; ++j) s += qT[j][b] * Wk[dd][j];
    u16[((size_t)b*16 + h)*1024 + dc*32 + dd]       = (f16)s;
    u16[((size_t)b*16 + 8 + h)*1024 + dc*32 + dd]   = (f16)0.f;   // zero-pad row (replaces memset)
  }
}

// ---------------- lgk: logits[b][n][h] = sum_d x[b][n][d] * u16[b][h][d] (MFMA, 1 wave) ----
__global__ __launch_bounds__(64) void lgk(const float* __restrict__ x, const f16* __restrict__ u16,
                                          float* __restrict__ logitbuf) {
  int mt = blockIdx.x, b = blockIdx.y;
  int lane = threadIdx.x, l15 = lane & 15, l4 = lane >> 4;
  const float* Ap = x + ((size_t)b*256 + mt*16 + l15)*1024 + 8*l4;
  const f16* Bp = u16 + ((size_t)b*16 + l15)*1024 + 8*l4;
  f32x4 acc = (f32x4){0.f,0.f,0.f,0.f};
#pragma unroll 8
  for (int ks = 0; ks < 32; ++ks) {
    f32x4 lo = *(const f32x4*)(Ap + ks*32);
    f32x4 hi = *(const f32x4*)(Ap + ks*32 + 4);
    half8 h;
    h[0]=(f16)lo[0]; h[1]=(f16)lo[1]; h[2]=(f16)lo[2]; h[3]=(f16)lo[3];
    h[4]=(f16)hi[0]; h[5]=(f16)hi[1]; h[6]=(f16)hi[2]; h[7]=(f16)hi[3];
    acc = __builtin_amdgcn_mfma_f32_16x16x32_f16(h, *(const half8*)(Bp + ks*32), acc, 0,0,0);
  }
  if (l15 < 8) {
#pragma unroll
    for (int j = 0; j < 4; ++j)
      logitbuf[((size_t)b*256 + mt*16 + 4*l4 + j)*8 + l15] = acc[j];
  }
}

// ---------------- sm: softmax over n per (b,h); writes attnW f16 [b][16][256] (h>=8 zero) ----
__global__ __launch_bounds__(256) void sm(const float* __restrict__ logitbuf, f16* __restrict__ attnW) {
  int b = blockIdx.x, t = threadIdx.x;
  __shared__ float eL[256][9];
  __shared__ float Zs[8];
  float e[8];
  const float* lp = logitbuf + (size_t)b*256*8 + (size_t)t*8;
#pragma unroll
  for (int h = 0; h < 8; ++h) { e[h] = __expf(lp[h] * SCALE); eL[t][h] = e[h]; }
  __syncthreads();
  {
    int h = t >> 5, i = t & 31;
    float s = 0.f;
#pragma unroll
    for (int k = 0; k < 8; ++k) s += eL[i + 32*k][h];
#pragma unroll
    for (int o = 1; o < 32; o <<= 1) s += __shfl_xor(s, o);
    if (i == 0) Zs[h] = s;
  }
  __syncthreads();
#pragma unroll
  for (int h = 0; h < 8; ++h) attnW[((size_t)b*16 + h)*256 + t] = (f16)(e[h] / Zs[h]);
#pragma unroll
  for (int h = 8; h < 16; ++h) attnW[((size_t)b*16 + h)*256 + t] = (f16)0.f;
}

// ---------------- xbk: xbar[b][h][d] = sum_n attnW[b][h][n] * x[b][n][d] via xT (MFMA, 1 wave) ----
__global__ __launch_bounds__(64) void xbk(const f16* __restrict__ attnW, const f16* __restrict__ xT,
                                          f16* __restrict__ xbar) {
  int dt = blockIdx.x, b = blockIdx.y;
  int lane = threadIdx.x, l15 = lane & 15, l4 = lane >> 4;
  const f16* Ap = attnW + ((size_t)b*16 + l15)*256 + 8*l4;
  const f16* Bp = xT + ((size_t)b*1024 + dt*16 + l15)*256 + 8*l4;
  f32x4 acc = (f32x4){0.f,0.f,0.f,0.f};
#pragma unroll
  for (int ks = 0; ks < 8; ++ks)
    acc = __builtin_amdgcn_mfma_f32_16x16x32_f16(*(const half8*)(Ap + ks*32),
                                                 *(const half8*)(Bp + ks*32), acc, 0,0,0);
  if (l4 < 2) {
#pragma unroll
    for (int j = 0; j < 4; ++j)
      xbar[((size_t)b*8 + 4*l4 + j)*1024 + dt*16 + l15] = (f16)acc[j];
  }
}

// ---------------- vk: attnout[b][h*64+j] += sum_d xbar[b][h][d] * Wkv[d][512+h*64+j] ----
__global__ __launch_bounds__(256) void vk(const f16* __restrict__ xbar, const float* __restrict__ Wkv,
                                          float* __restrict__ attnout) {
  int h = blockIdx.x, dc = blockIdx.y, bc = blockIdx.z;
  int t = threadIdx.x;
  __shared__ float Wv[256][64];
  {
    int j = t & 63, g = t >> 6;
#pragma unroll
    for (int rr = 0; rr < 64; ++rr) {
      int dd = g*64 + rr;
      Wv[dd][j] = Wkv[(size_t)(dc*256 + dd)*1024 + 512 + h*64 + j];
    }
  }
  __syncthreads();
  int j = t & 63, bq = t >> 6;
  float s[4] = {0.f,0.f,0.f,0.f};
  const f16* xp[4];
#pragma unroll
  for (int bl = 0; bl < 4; ++bl)
    xp[bl] = xbar + ((size_t)(bc*16 + bq*4 + bl)*8 + h)*1024 + dc*256;
  for (int d8 = 0; d8 < 32; ++d8) {
    half8 xv[4];
#pragma unroll
    for (int bl = 0; bl < 4; ++bl) xv[bl] = *(const half8*)(xp[bl] + d8*8);
#pragma unroll
    for (int i = 0; i < 8; ++i) {
      float w = Wv[d8*8 + i][j];
#pragma unroll
      for (int bl = 0; bl < 4; ++bl) s[bl] += (float)xv[bl][i] * w;
    }
  }
#pragma unroll
  for (int bl = 0; bl < 4; ++bl)
    atomicAdd(&attnout[(size_t)(bc*16 + bq*4 + bl)*512 + h*64 + j], s[bl]);
}

// ---------------- spatialf: fused spatial = attnout @ Wout + bout; grid (4 ec, 64 b) ----
__global__ __launch_bounds__(256) void spatialf(const float* __restrict__ attnout, const float* __restrict__ Wout,
                                                const float* __restrict__ bout, float* __restrict__ spatial) {
  int ec = blockIdx.x, b = blockIdx.y;
  int t = threadIdx.x;
  __shared__ float ao[512];
  ao[t]       = attnout[(size_t)b*512 + t];
  ao[t + 256] = attnout[(size_t)b*512 + 256 + t];
  __syncthreads();
  int e = ec*256 + t;
  float a0 = bout[e], a1 = 0.f;
#pragma unroll 8
  for (int i = 0; i < 512; i += 2) {
    a0 += ao[i]     * Wout[(size_t)i*1024 + e];
    a1 += ao[i + 1] * Wout[(size_t)(i + 1)*1024 + e];
  }
  spatial[(size_t)b*1024 + e] = a0 + a1;
}

// ---------------- spec v11 (proven 72us config): 16 free-running waves at 4/SIMD;
// 3-bit A-swizzle; per-wave private B dbuf + counted vmcnt; LDS 160 KiB ----
__global__ __launch_bounds__(1024, 4) void speck(const f16* __restrict__ Y, const f16* __restrict__ xT,
                                                 const float* __restrict__ spatial, float* __restrict__ r) {
  __shared__ __attribute__((aligned(16))) char smem[163840];
  f16* As = (f16*)smem;                       // 32 KB: [64 r][32 slot16], slot swizzled by row&7
  f16* Bs = (f16*)(smem + 32768);             // 128 KB: [16 wave][2 slot][64 r][4 chunk][8 f16]
  float* sz   = (float*)smem;                 // post-loop alias of As (fenced by syncthreads)
  float* zfin = (float*)(smem + 4096);
  int bid = blockIdx.x;
  int xcd = bid & 7, q = bid >> 3;
  int b = xcd*8 + (q >> 4);                   // batch pinned to one XCD
  int iblk = q & 15;
  int t = threadIdx.x, lane = t & 63, wave = t >> 6;
  int l15 = lane & 15, l4 = lane >> 4;
  const f16* Yb  = Y  + (size_t)b*262144;
  const f16* xTb = xT + (size_t)b*262144;
  int i0 = iblk*64;

  f32x4 acc[4][4];
#pragma unroll
  for (int mi=0;mi<4;++mi)
#pragma unroll
    for (int ni=0;ni<4;++ni) acc[mi][ni] = (f32x4){0.f,0.f,0.f,0.f};
  int pc = (l4 ^ ((l15 >> 1) & 3)) * 8;

  // ---- A stage: 64x256 Y tile, 2 GLL per wave; 3-bit row XOR on the SOURCE slot ----
#pragma unroll
  for (int g = 0; g < 2; ++g) {
    int u = (wave*2 + g)*64 + lane;           // linear 16B-slot index (write side)
    int rA = u >> 5, v = u & 31;
    int s = v ^ (rA & 7);                     // logical slot whose data lands at phys v
    GLL(Yb + (size_t)(i0 + rA)*256 + (s >> 2)*32 + (s & 3)*8, As + ((wave*2 + g)*64)*8);
  }
  // ---- per-wave private B stage: wave's 64 e-rows x 32 k -> 4 GLL (2-bit chunk XOR) ----
  auto STAGE_B = [&](int slot, int ks) {
    int k0 = ks*32;
#pragma unroll
    for (int c = 0; c < 4; ++c) {
      int u2 = c*64 + lane;
      int row = u2 >> 2, pchk = u2 & 3;
      int ch = pchk ^ (((row & 15) >> 1) & 3);
      GLL(xTb + (size_t)(wave*64 + row)*256 + k0 + ch*8,
          Bs + ((wave*2 + slot)*256 + c*64)*8);
    }
  };
  STAGE_B(0, 0);
  STAGE_B(1, 1);
  asm volatile("s_waitcnt vmcnt(8)" ::: "memory");   // own A landed (B0,B1 still in flight)
  __builtin_amdgcn_s_barrier();                      // all waves' A visible; ONLY loop barrier

  int axor = l15 & 7;                                // row&7 is mi-invariant (rows mi*16+l15)
#pragma unroll
  for (int ks = 0; ks < 8; ++ks) {
    int slot = ks & 1;
    if (ks < 7) asm volatile("s_waitcnt vmcnt(4)" ::: "memory");  // B(ks) landed, B(ks+1) in flight
    else        asm volatile("s_waitcnt vmcnt(0)" ::: "memory");
    __builtin_amdgcn_sched_barrier(0);
    half8 a[4], bb[4];
    const f16* Bbase = Bs + (wave*2 + slot)*2048;
    int physA = ((ks*4 + l4) ^ axor)*8;
#pragma unroll
    for (int mi = 0; mi < 4; ++mi) a[mi]  = *(const half8*)(As + (mi*16 + l15)*256 + physA);
#pragma unroll
    for (int ni = 0; ni < 4; ++ni) bb[ni] = *(const half8*)(Bbase + (ni*16 + l15)*32 + pc);
    asm volatile("s_waitcnt lgkmcnt(0)" ::: "memory");   // frags in regs -> slot reusable
    __builtin_amdgcn_sched_barrier(0);
    if (ks < 6) STAGE_B(slot, ks + 2);
    __builtin_amdgcn_s_setprio(1);
#pragma unroll
    for (int ni = 0; ni < 4; ++ni)
#pragma unroll
      for (int mi = 0; mi < 4; ++mi)
        acc[mi][ni] = __builtin_amdgcn_mfma_f32_16x16x32_f16(a[mi], bb[ni], acc[mi][ni], 0,0,0);
    __builtin_amdgcn_s_setprio(0);
    __builtin_amdgcn_sched_barrier(0);
  }
  // ---- no-max softmax (f32-safe): exp in place; wave-local row partials in regs ----
  float zr[4][4];
#pragma unroll
  for (int mi=0;mi<4;++mi)
#pragma unroll
    for (int jj=0;jj<4;++jj) {
      float s = 0.f;
#pragma unroll
      for (int ni=0;ni<4;++ni) {
        float e = __expf(acc[mi][ni][jj]);
        acc[mi][ni][jj] = e;
        s += e;
      }
#pragma unroll
      for (int o=1;o<16;o<<=1) s += __shfl_xor(s, o);
      zr[mi][jj] = s;
    }
  __syncthreads();                                   // all waves done with As -> alias as sz
  if (l15 == 0) {
#pragma unroll
    for (int mi=0;mi<4;++mi)
#pragma unroll
      for (int jj=0;jj<4;++jj) sz[(mi*16 + 4*l4 + jj)*16 + wave] = zr[mi][jj];
  }
  __syncthreads();
  {
    float v = sz[t];                                 // t = row*16 + w
#pragma unroll
    for (int o=1;o<16;o<<=1) v += __shfl_xor(v, o);
    if ((t & 15) == 0) zfin[t >> 4] = v;
  }
  __syncthreads();
  float f[4][4];
#pragma unroll
  for (int mi=0;mi<4;++mi)
#pragma unroll
    for (int jj=0;jj<4;++jj) {
      int row = mi*16 + 4*l4 + jj;
      f[mi][jj] = spatial[(size_t)b*1024 + i0 + row] / zfin[row];
    }
  float* rb = r + (size_t)b*1024;
#pragma unroll
  for (int ni=0;ni<4;++ni) {
    float v = 0.f;
#pragma unroll
    for (int mi=0;mi<4;++mi)
#pragma unroll
      for (int jj=0;jj<4;++jj) v += f[mi][jj]*acc[mi][ni][jj];
    v += __shfl_xor(v, 16);
    v += __shfl_xor(v, 32);
    if (l4 == 0) atomicAdd(rb + wave*64 + ni*16 + l15, v);
  }
}

// ---------------- broadcast: out[b,n,:] = r[b,:] ----------------
__global__ __launch_bounds__(256) void bcast(const float* __restrict__ r, float* __restrict__ out) {
  size_t row = blockIdx.x;
  int b = (int)(row >> 8);
  f32x4 v = *(const f32x4*)(r + (size_t)b*1024 + threadIdx.x*4);
  *(f32x4*)(out + row*1024 + (size_t)threadIdx.x*4) = v;
}

extern "C" void kernel_launch(void* const* d_in, const int* in_sizes, int n_in,
                              void* d_out, int out_size, void* d_ws, size_t ws_size,
                              hipStream_t stream) {
  const float* x     = (const float*)d_in[0];
  const float* Wq    = (const float*)d_in[1];
  const float* Wkv   = (const float*)d_in[2];
  const float* Wout  = (const float*)d_in[3];
  const float* bout  = (const float*)d_in[4];
  const float* Wspec = (const float*)d_in[5];
  float* out = (float*)d_out;
  char* ws = (char*)d_ws;
  // workspace aliases (stream-ordered):
  //   ws+0..32M:  Y (gemm_qs -> speck). Aliases while Y dead: u16pad@0,
  //               logitbuf@2M, attnW@2.5M, xbar@3M, qbuf@5.25M
  //   ws+32M:     MT 128KB; ws+64M: xT 32MB; ws+98M+: Wspec16/attnout/spatial/rvec
  f16*   Ybuf     = (f16*)(ws);
  f16*   u16pad   = (f16*)(ws);
  float* logitbuf = (float*)(ws + 2097152);
  f16*   attnW    = (f16*)(ws + 2621440);
  f16*   xbar     = (f16*)(ws + 3145728);
  float* qbuf     = (float*)(ws + 5242880);
  f16*   MT       = (f16*)(ws + 33554432);
  f16*   xT       = (f16*)(ws + 67108864);
  f16*   Wspec16  = (f16*)(ws + 102760448);
  float* attnout  = (float*)(ws + 103022592);
  float* spatial  = (float*)(ws + 103153664);
  float* rvec     = (float*)(ws + 103415808);
  (void)in_sizes; (void)n_in; (void)out_size; (void)ws_size;

  prep_xT     <<<dim3(32, 4, 64), dim3(256), 0, stream>>>(x, xT);
  prep_Wspec16<<<dim3(256),       dim3(256), 0, stream>>>(Wspec, Wspec16);
  // MT[m][n] = sum_j Wk[m][j]*Wq[n][j]  (256x256)
  gemm128<8,512,512,256,false><<<dim3(2, 2, 1), dim3(256), 0, stream>>>(Wspec16 + 256, Wspec16, MT, 0, 0, 0);
  hipMemsetAsync(attnout, 0, 64*512*sizeof(float), stream);
  qk          <<<dim3(64, 8),     dim3(256), 0, stream>>>(x, Wq, qbuf);
  uk          <<<dim3(8, 32),     dim3(256), 0, stream>>>(Wkv, qbuf, u16pad);
  lgk         <<<dim3(16, 64),    dim3(64),  0, stream>>>(x, u16pad, logitbuf);
  sm          <<<dim3(64),        dim3(256), 0, stream>>>(logitbuf, attnW);
  xbk         <<<dim3(64, 64),    dim3(64),  0, stream>>>(attnW, xT, xbar);
  vk          <<<dim3(8, 4, 4),   dim3(256), 0, stream>>>(xbar, Wkv, attnout);
  spatialf    <<<dim3(4, 64),     dim3(256), 0, stream>>>(attnout, Wout, bout, spatial);
  // Y[b] = xT[b] @ MT^T * SCALE  (1024x256, K=256)
  gemm128<8,256,256,256,true><<<dim3(8, 2, 64), dim3(256), 0, stream>>>(xT, MT, Ybuf,
                                                                        262144, 0, 262144);
  hipMemsetAsync(rvec, 0, 64*1024*sizeof(float), stream);
  speck       <<<dim3(1024),      dim3(1024), 0, stream>>>(Ybuf, xT, spatial, rvec);
  bcast       <<<dim3(16384),     dim3(256), 0, stream>>>(rvec, out);
}

// Round 18
// 210.836 us; speedup vs baseline: 1.1973x; 1.0126x over previous
//
#include <hip/hip_runtime.h>
#include <hip/hip_bf16.h>
#include <cstdint>

typedef _Float16 f16;
typedef _Float16 half8 __attribute__((ext_vector_type(8)));
typedef float f32x4 __attribute__((ext_vector_type(4)));

#define SCALE 0.125f

// async global->LDS, 16B per lane, dest = wave-uniform base + lane*16
#define GLL(src, dst) __builtin_amdgcn_global_load_lds( \
    (const __attribute__((address_space(1))) unsigned int*)(src), \
    (__attribute__((address_space(3))) unsigned int*)(dst), 16, 0, 0)

// ---------------- prep: x (64,256,1024) f32 -> xT (64,1024,256) f16 (vectorized both sides) ----
__global__ __launch_bounds__(256) void prep_xT(const float* __restrict__ x, f16* __restrict__ xT) {
  __shared__ f16 tile[64][34];                 // 64 n x 32 d, pad 34
  int dt = blockIdx.x, nt = blockIdx.y, b = blockIdx.z;
  int t = threadIdx.x;
#pragma unroll
  for (int p = 0; p < 2; ++p) {
    int n = p*32 + (t >> 3), dg = t & 7;
    f32x4 v = *(const f32x4*)(x + ((size_t)b*256 + nt*64 + n)*1024 + dt*32 + dg*4);
    f16* dst = &tile[n][dg*4];
    dst[0] = (f16)v[0]; dst[1] = (f16)v[1]; dst[2] = (f16)v[2]; dst[3] = (f16)v[3];
  }
  __syncthreads();
  {
    int d = t >> 3, ng = t & 7;
    half8 o;
#pragma unroll
    for (int j = 0; j < 8; ++j) o[j] = tile[ng*8 + j][d];
    *(half8*)(xT + ((size_t)b*1024 + dt*32 + d)*256 + nt*64 + ng*8) = o;
  }
}

// ---------------- prep: Wspec (256,768) f32 -> Wspec16 [256][512] f16 (first 512 cols) ----
__global__ __launch_bounds__(256) void prep_Wspec16(const float* __restrict__ W, f16* __restrict__ Wt) {
  int row = blockIdx.x, t = threadIdx.x;
  Wt[(size_t)row*512 + t]       = (f16)W[(size_t)row*768 + t];
  Wt[(size_t)row*512 + 256 + t] = (f16)W[(size_t)row*768 + 256 + t];
}

// ---------------- 128x128x(32*KSTEPS) f16 GEMM, double-buffered + counted vmcnt ----
template<int KSTEPS, int AST, int BST, int CST, bool SCALEQ>
__global__ __launch_bounds__(256) void gemm128(const f16* __restrict__ Ag, const f16* __restrict__ Bg,
                                               f16* __restrict__ Cg, size_t aB, size_t bB, size_t cB) {
  __shared__ f16 As[2][128*32];
  __shared__ f16 Bs[2][128*32];
  const f16* A = Ag + (size_t)blockIdx.z*aB;
  const f16* B = Bg + (size_t)blockIdx.z*bB;
  f16* C = Cg + (size_t)blockIdx.z*cB;
  int t = threadIdx.x, lane = t & 63, wave = t >> 6;
  int l15 = lane & 15, l4 = lane >> 4;
  int wm = wave & 1, wn = wave >> 1;
  size_t m0 = (size_t)blockIdx.x*128, n0 = (size_t)blockIdx.y*128;
  f32x4 acc[4][4];
#pragma unroll
  for (int i=0;i<4;++i)
#pragma unroll
    for (int j=0;j<4;++j) acc[i][j] = (f32x4){0.f,0.f,0.f,0.f};
  int rowS[2], chS[2];
#pragma unroll
  for (int c=0;c<2;++c) {
    int slot = c*256 + t;
    rowS[c] = slot >> 2;
    chS[c]  = (slot & 3) ^ ((slot >> 3) & 3);
  }
  int pc = (l4 ^ ((l15 >> 1) & 3)) * 8;

  auto STAGE = [&](int buf, int ks) {
    int k0 = ks*32;
#pragma unroll
    for (int c=0;c<2;++c) {
      GLL(A + (m0 + rowS[c])*(size_t)AST + k0 + chS[c]*8, &As[buf][(c*256 + wave*64)*8]);
      GLL(B + (n0 + rowS[c])*(size_t)BST + k0 + chS[c]*8, &Bs[buf][(c*256 + wave*64)*8]);
    }
  };

  STAGE(0, 0);
#pragma unroll 2
  for (int ks = 0; ks < KSTEPS; ++ks) {
    int cur = ks & 1;
    if (ks + 1 < KSTEPS) {
      STAGE(cur ^ 1, ks + 1);
      asm volatile("s_waitcnt vmcnt(4)" ::: "memory");
    } else {
      asm volatile("s_waitcnt vmcnt(0)" ::: "memory");
    }
    __builtin_amdgcn_s_barrier();
    __builtin_amdgcn_sched_barrier(0);
    half8 a[4], bb[4];
    const f16* Af = &As[cur][(wm*64 + l15)*32 + pc];
    const f16* Bf = &Bs[cur][(wn*64 + l15)*32 + pc];
#pragma unroll
    for (int mi=0;mi<4;++mi) a[mi]  = *(const half8*)(Af + mi*16*32);
#pragma unroll
    for (int ni=0;ni<4;++ni) bb[ni] = *(const half8*)(Bf + ni*16*32);
    __builtin_amdgcn_s_setprio(1);
#pragma unroll
    for (int mi=0;mi<4;++mi)
#pragma unroll
      for (int ni=0;ni<4;++ni)
        acc[mi][ni] = __builtin_amdgcn_mfma_f32_16x16x32_f16(a[mi], bb[ni], acc[mi][ni], 0,0,0);
    __builtin_amdgcn_s_setprio(0);
    __builtin_amdgcn_sched_barrier(0);
    __builtin_amdgcn_s_barrier();
  }
  float cscale = SCALEQ ? SCALE : 1.0f;
#pragma unroll
  for (int mi=0;mi<4;++mi)
#pragma unroll
    for (int ni=0;ni<4;++ni)
#pragma unroll
      for (int j=0;j<4;++j) {
        size_t row = m0 + wm*64 + mi*16 + 4*l4 + j;
        size_t col = n0 + wn*64 + ni*16 + l15;
        C[row*CST + col] = (f16)(acc[mi][ni][j] * cscale);
      }
}

// ---------------- qk: q[b][h*64+d] = x_center @ Wq slice (f32); also zeroes attnout slice ----
__global__ __launch_bounds__(256) void qk(const float* __restrict__ x, const float* __restrict__ Wq,
                                          float* __restrict__ qbuf, float* __restrict__ attnout) {
  int b = blockIdx.x, h = blockIdx.y;
  int t = threadIdx.x;
  __shared__ float xc[1024];
  __shared__ float part[4][64];
  if (t < 64) attnout[(size_t)b*512 + h*64 + t] = 0.f;   // replaces memset dispatch
  const float* xcg = x + ((size_t)b*256 + 128)*1024;
#pragma unroll
  for (int i = 0; i < 4; ++i) xc[t + 256*i] = xcg[t + 256*i];
  __syncthreads();
  int d = t & 63, chunk = t >> 6;
  float s = 0.f;
  const float* wq = Wq + (size_t)(chunk*256)*512 + h*64 + d;
#pragma unroll 8
  for (int c = 0; c < 256; ++c) s += xc[chunk*256 + c] * wq[(size_t)c*512];
  part[chunk][d] = s;
  __syncthreads();
  if (t < 64) qbuf[(size_t)b*512 + h*64 + t] = part[0][t]+part[1][t]+part[2][t]+part[3][t];
}

// ---------------- uk: u16[b][h][d] = sum_j Wkv[d][h*64+j] * q[b][h][j]; also zeroes pad rows ----
__global__ __launch_bounds__(256) void uk(const float* __restrict__ Wkv, const float* __restrict__ qbuf,
                                          f16* __restrict__ u16) {
  int h = blockIdx.x, dc = blockIdx.y;
  int t = threadIdx.x;
  __shared__ float Wk[32][64];
  __shared__ float qT[64][65];
  {
    int j = t & 63, g = t >> 6;
#pragma unroll
    for (int rr = 0; rr < 8; ++rr) {
      int dd = g*8 + rr;
      Wk[dd][j] = Wkv[(size_t)(dc*32 + dd)*1024 + h*64 + j];
    }
#pragma unroll
    for (int rr = 0; rr < 16; ++rr) {
      int bb = g*16 + rr;
      qT[j][bb] = qbuf[(size_t)bb*512 + h*64 + j];
    }
  }
  __syncthreads();
  int b = t & 63, dq = t >> 6;
#pragma unroll
  for (int i = 0; i < 8; ++i) {
    int dd = dq*8 + i;
    float s = 0.f;
#pragma unroll 8
    for (int j = 0; j < 64; ++j) s += qT[j][b] * Wk[dd][j];
    u16[((size_t)b*16 + h)*1024 + dc*32 + dd]       = (f16)s;
    u16[((size_t)b*16 + 8 + h)*1024 + dc*32 + dd]   = (f16)0.f;
  }
}

// ---------------- lgk: logits[b][n][h] = sum_d x[b][n][d] * u16[b][h][d] (MFMA, 1 wave) ----
__global__ __launch_bounds__(64) void lgk(const float* __restrict__ x, const f16* __restrict__ u16,
                                          float* __restrict__ logitbuf) {
  int mt = blockIdx.x, b = blockIdx.y;
  int lane = threadIdx.x, l15 = lane & 15, l4 = lane >> 4;
  const float* Ap = x + ((size_t)b*256 + mt*16 + l15)*1024 + 8*l4;
  const f16* Bp = u16 + ((size_t)b*16 + l15)*1024 + 8*l4;
  f32x4 acc = (f32x4){0.f,0.f,0.f,0.f};
#pragma unroll 8
  for (int ks = 0; ks < 32; ++ks) {
    f32x4 lo = *(const f32x4*)(Ap + ks*32);
    f32x4 hi = *(const f32x4*)(Ap + ks*32 + 4);
    half8 h;
    h[0]=(f16)lo[0]; h[1]=(f16)lo[1]; h[2]=(f16)lo[2]; h[3]=(f16)lo[3];
    h[4]=(f16)hi[0]; h[5]=(f16)hi[1]; h[6]=(f16)hi[2]; h[7]=(f16)hi[3];
    acc = __builtin_amdgcn_mfma_f32_16x16x32_f16(h, *(const half8*)(Bp + ks*32), acc, 0,0,0);
  }
  if (l15 < 8) {
#pragma unroll
    for (int j = 0; j < 4; ++j)
      logitbuf[((size_t)b*256 + mt*16 + 4*l4 + j)*8 + l15] = acc[j];
  }
}

// ---------------- xbk v2 (sm FUSED): softmax-on-the-fly from logitbuf, then
// xbar[b][h][d] = sum_n attnW[b][h][n] * xT[b][d][n] (MFMA, 1 wave) ----
__global__ __launch_bounds__(64) void xbk(const float* __restrict__ logitbuf, const f16* __restrict__ xT,
                                          f16* __restrict__ xbar) {
  int dt = blockIdx.x, b = blockIdx.y;
  int lane = threadIdx.x, l15 = lane & 15, l4 = lane >> 4;
  const float* lp = logitbuf + (size_t)b*256*8;
  // Z for head h=l15 (h<8): lane sums n = l4*64 .. +63, then combine across l4 group
  float Z = 0.f;
  if (l15 < 8) {
#pragma unroll 8
    for (int n = l4*64; n < l4*64 + 64; ++n)
      Z += __expf(lp[(size_t)n*8 + l15] * SCALE);
  }
  Z += __shfl_xor(Z, 16);
  Z += __shfl_xor(Z, 32);
  float rZ = (l15 < 8) ? (1.0f / Z) : 0.f;
  const f16* Bp = xT + ((size_t)b*1024 + dt*16 + l15)*256 + 8*l4;
  f32x4 acc = (f32x4){0.f,0.f,0.f,0.f};
#pragma unroll
  for (int ks = 0; ks < 8; ++ks) {
    half8 a;
    if (l15 < 8) {
#pragma unroll
      for (int j = 0; j < 8; ++j) {
        int n = ks*32 + l4*8 + j;
        a[j] = (f16)(__expf(lp[(size_t)n*8 + l15] * SCALE) * rZ);
      }
    } else {
#pragma unroll
      for (int j = 0; j < 8; ++j) a[j] = (f16)0.f;
    }
    acc = __builtin_amdgcn_mfma_f32_16x16x32_f16(a, *(const half8*)(Bp + ks*32), acc, 0,0,0);
  }
  if (l4 < 2) {
#pragma unroll
    for (int j = 0; j < 4; ++j)
      xbar[((size_t)b*8 + 4*l4 + j)*1024 + dt*16 + l15] = (f16)acc[j];
  }
}

// ---------------- vk: attnout[b][h*64+j] += sum_d xbar[b][h][d] * Wkv[d][512+h*64+j] ----
__global__ __launch_bounds__(256) void vk(const f16* __restrict__ xbar, const float* __restrict__ Wkv,
                                          float* __restrict__ attnout) {
  int h = blockIdx.x, dc = blockIdx.y, bc = blockIdx.z;
  int t = threadIdx.x;
  __shared__ float Wv[256][64];
  {
    int j = t & 63, g = t >> 6;
#pragma unroll
    for (int rr = 0; rr < 64; ++rr) {
      int dd = g*64 + rr;
      Wv[dd][j] = Wkv[(size_t)(dc*256 + dd)*1024 + 512 + h*64 + j];
    }
  }
  __syncthreads();
  int j = t & 63, bq = t >> 6;
  float s[4] = {0.f,0.f,0.f,0.f};
  const f16* xp[4];
#pragma unroll
  for (int bl = 0; bl < 4; ++bl)
    xp[bl] = xbar + ((size_t)(bc*16 + bq*4 + bl)*8 + h)*1024 + dc*256;
  for (int d8 = 0; d8 < 32; ++d8) {
    half8 xv[4];
#pragma unroll
    for (int bl = 0; bl < 4; ++bl) xv[bl] = *(const half8*)(xp[bl] + d8*8);
#pragma unroll
    for (int i = 0; i < 8; ++i) {
      float w = Wv[d8*8 + i][j];
#pragma unroll
      for (int bl = 0; bl < 4; ++bl) s[bl] += (float)xv[bl][i] * w;
    }
  }
#pragma unroll
  for (int bl = 0; bl < 4; ++bl)
    atomicAdd(&attnout[(size_t)(bc*16 + bq*4 + bl)*512 + h*64 + j], s[bl]);
}

// ---------------- spatialf: fused spatial = attnout @ Wout + bout; also zeroes rvec slice ----
__global__ __launch_bounds__(256) void spatialf(const float* __restrict__ attnout, const float* __restrict__ Wout,
                                                const float* __restrict__ bout, float* __restrict__ spatial,
                                                float* __restrict__ rvec) {
  int ec = blockIdx.x, b = blockIdx.y;
  int t = threadIdx.x;
  __shared__ float ao[512];
  rvec[(size_t)b*1024 + ec*256 + t] = 0.f;     // replaces memset dispatch (pre-speck, stream-ordered)
  ao[t]       = attnout[(size_t)b*512 + t];
  ao[t + 256] = attnout[(size_t)b*512 + 256 + t];
  __syncthreads();
  int e = ec*256 + t;
  float a0 = bout[e], a1 = 0.f;
#pragma unroll 8
  for (int i = 0; i < 512; i += 2) {
    a0 += ao[i]     * Wout[(size_t)i*1024 + e];
    a1 += ao[i + 1] * Wout[(size_t)(i + 1)*1024 + e];
  }
  spatial[(size_t)b*1024 + e] = a0 + a1;
}

// ---------------- spec v11 (proven 72us config): 16 free-running waves at 4/SIMD;
// 3-bit A-swizzle; per-wave private B dbuf + counted vmcnt; LDS 160 KiB ----
__global__ __launch_bounds__(1024, 4) void speck(const f16* __restrict__ Y, const f16* __restrict__ xT,
                                                 const float* __restrict__ spatial, float* __restrict__ r) {
  __shared__ __attribute__((aligned(16))) char smem[163840];
  f16* As = (f16*)smem;                       // 32 KB: [64 r][32 slot16], slot swizzled by row&7
  f16* Bs = (f16*)(smem + 32768);             // 128 KB: [16 wave][2 slot][64 r][4 chunk][8 f16]
  float* sz   = (float*)smem;                 // post-loop alias of As (fenced by syncthreads)
  float* zfin = (float*)(smem + 4096);
  int bid = blockIdx.x;
  int xcd = bid & 7, q = bid >> 3;
  int b = xcd*8 + (q >> 4);                   // batch pinned to one XCD
  int iblk = q & 15;
  int t = threadIdx.x, lane = t & 63, wave = t >> 6;
  int l15 = lane & 15, l4 = lane >> 4;
  const f16* Yb  = Y  + (size_t)b*262144;
  const f16* xTb = xT + (size_t)b*262144;
  int i0 = iblk*64;

  f32x4 acc[4][4];
#pragma unroll
  for (int mi=0;mi<4;++mi)
#pragma unroll
    for (int ni=0;ni<4;++ni) acc[mi][ni] = (f32x4){0.f,0.f,0.f,0.f};
  int pc = (l4 ^ ((l15 >> 1) & 3)) * 8;

  // ---- A stage: 64x256 Y tile, 2 GLL per wave; 3-bit row XOR on the SOURCE slot ----
#pragma unroll
  for (int g = 0; g < 2; ++g) {
    int u = (wave*2 + g)*64 + lane;           // linear 16B-slot index (write side)
    int rA = u >> 5, v = u & 31;
    int s = v ^ (rA & 7);                     // logical slot whose data lands at phys v
    GLL(Yb + (size_t)(i0 + rA)*256 + (s >> 2)*32 + (s & 3)*8, As + ((wave*2 + g)*64)*8);
  }
  // ---- per-wave private B stage: wave's 64 e-rows x 32 k -> 4 GLL (2-bit chunk XOR) ----
  auto STAGE_B = [&](int slot, int ks) {
    int k0 = ks*32;
#pragma unroll
    for (int c = 0; c < 4; ++c) {
      int u2 = c*64 + lane;
      int row = u2 >> 2, pchk = u2 & 3;
      int ch = pchk ^ (((row & 15) >> 1) & 3);
      GLL(xTb + (size_t)(wave*64 + row)*256 + k0 + ch*8,
          Bs + ((wave*2 + slot)*256 + c*64)*8);
    }
  };
  STAGE_B(0, 0);
  STAGE_B(1, 1);
  asm volatile("s_waitcnt vmcnt(8)" ::: "memory");   // own A landed (B0,B1 still in flight)
  __builtin_amdgcn_s_barrier();                      // all waves' A visible; ONLY loop barrier

  int axor = l15 & 7;                                // row&7 is mi-invariant (rows mi*16+l15)
#pragma unroll
  for (int ks = 0; ks < 8; ++ks) {
    int slot = ks & 1;
    if (ks < 7) asm volatile("s_waitcnt vmcnt(4)" ::: "memory");  // B(ks) landed, B(ks+1) in flight
    else        asm volatile("s_waitcnt vmcnt(0)" ::: "memory");
    __builtin_amdgcn_sched_barrier(0);
    half8 a[4], bb[4];
    const f16* Bbase = Bs + (wave*2 + slot)*2048;
    int physA = ((ks*4 + l4) ^ axor)*8;
#pragma unroll
    for (int mi = 0; mi < 4; ++mi) a[mi]  = *(const half8*)(As + (mi*16 + l15)*256 + physA);
#pragma unroll
    for (int ni = 0; ni < 4; ++ni) bb[ni] = *(const half8*)(Bbase + (ni*16 + l15)*32 + pc);
    asm volatile("s_waitcnt lgkmcnt(0)" ::: "memory");   // frags in regs -> slot reusable
    __builtin_amdgcn_sched_barrier(0);
    if (ks < 6) STAGE_B(slot, ks + 2);
    __builtin_amdgcn_s_setprio(1);
#pragma unroll
    for (int ni = 0; ni < 4; ++ni)
#pragma unroll
      for (int mi = 0; mi < 4; ++mi)
        acc[mi][ni] = __builtin_amdgcn_mfma_f32_16x16x32_f16(a[mi], bb[ni], acc[mi][ni], 0,0,0);
    __builtin_amdgcn_s_setprio(0);
    __builtin_amdgcn_sched_barrier(0);
  }
  // ---- no-max softmax (f32-safe): exp in place; wave-local row partials in regs ----
  float zr[4][4];
#pragma unroll
  for (int mi=0;mi<4;++mi)
#pragma unroll
    for (int jj=0;jj<4;++jj) {
      float s = 0.f;
#pragma unroll
      for (int ni=0;ni<4;++ni) {
        float e = __expf(acc[mi][ni][jj]);
        acc[mi][ni][jj] = e;
        s += e;
      }
#pragma unroll
      for (int o=1;o<16;o<<=1) s += __shfl_xor(s, o);
      zr[mi][jj] = s;
    }
  __syncthreads();                                   // all waves done with As -> alias as sz
  if (l15 == 0) {
#pragma unroll
    for (int mi=0;mi<4;++mi)
#pragma unroll
      for (int jj=0;jj<4;++jj) sz[(mi*16 + 4*l4 + jj)*16 + wave] = zr[mi][jj];
  }
  __syncthreads();
  {
    float v = sz[t];                                 // t = row*16 + w
#pragma unroll
    for (int o=1;o<16;o<<=1) v += __shfl_xor(v, o);
    if ((t & 15) == 0) zfin[t >> 4] = v;
  }
  __syncthreads();
  float f[4][4];
#pragma unroll
  for (int mi=0;mi<4;++mi)
#pragma unroll
    for (int jj=0;jj<4;++jj) {
      int row = mi*16 + 4*l4 + jj;
      f[mi][jj] = spatial[(size_t)b*1024 + i0 + row] / zfin[row];
    }
  float* rb = r + (size_t)b*1024;
#pragma unroll
  for (int ni=0;ni<4;++ni) {
    float v = 0.f;
#pragma unroll
    for (int mi=0;mi<4;++mi)
#pragma unroll
      for (int jj=0;jj<4;++jj) v += f[mi][jj]*acc[mi][ni][jj];
    v += __shfl_xor(v, 16);
    v += __shfl_xor(v, 32);
    if (l4 == 0) atomicAdd(rb + wave*64 + ni*16 + l15, v);
  }
}

// ---------------- broadcast: out[b,n,:] = r[b,:] ----------------
__global__ __launch_bounds__(256) void bcast(const float* __restrict__ r, float* __restrict__ out) {
  size_t row = blockIdx.x;
  int b = (int)(row >> 8);
  f32x4 v = *(const f32x4*)(r + (size_t)b*1024 + threadIdx.x*4);
  *(f32x4*)(out + row*1024 + (size_t)threadIdx.x*4) = v;
}

extern "C" void kernel_launch(void* const* d_in, const int* in_sizes, int n_in,
                              void* d_out, int out_size, void* d_ws, size_t ws_size,
                              hipStream_t stream) {
  const float* x     = (const float*)d_in[0];
  const float* Wq    = (const float*)d_in[1];
  const float* Wkv   = (const float*)d_in[2];
  const float* Wout  = (const float*)d_in[3];
  const float* bout  = (const float*)d_in[4];
  const float* Wspec = (const float*)d_in[5];
  float* out = (float*)d_out;
  char* ws = (char*)d_ws;
  // workspace aliases (stream-ordered):
  //   ws+0..32M:  Y (gemm_qs -> speck). Aliases while Y dead: u16pad@0,
  //               logitbuf@2M, xbar@3M, qbuf@5.25M
  //   ws+32M:     MT 128KB; ws+64M: xT 32MB; ws+98M+: Wspec16/attnout/spatial/rvec
  f16*   Ybuf     = (f16*)(ws);
  f16*   u16pad   = (f16*)(ws);
  float* logitbuf = (float*)(ws + 2097152);
  f16*   xbar     = (f16*)(ws + 3145728);
  float* qbuf     = (float*)(ws + 5242880);
  f16*   MT       = (f16*)(ws + 33554432);
  f16*   xT       = (f16*)(ws + 67108864);
  f16*   Wspec16  = (f16*)(ws + 102760448);
  float* attnout  = (float*)(ws + 103022592);
  float* spatial  = (float*)(ws + 103153664);
  float* rvec     = (float*)(ws + 103415808);
  (void)in_sizes; (void)n_in; (void)out_size; (void)ws_size;

  prep_xT     <<<dim3(32, 4, 64), dim3(256), 0, stream>>>(x, xT);
  prep_Wspec16<<<dim3(256),       dim3(256), 0, stream>>>(Wspec, Wspec16);
  // MT[m][n] = sum_j Wk[m][j]*Wq[n][j]  (256x256)
  gemm128<8,512,512,256,false><<<dim3(2, 2, 1), dim3(256), 0, stream>>>(Wspec16 + 256, Wspec16, MT, 0, 0, 0);
  qk          <<<dim3(64, 8),     dim3(256), 0, stream>>>(x, Wq, qbuf, attnout);
  uk          <<<dim3(8, 32),     dim3(256), 0, stream>>>(Wkv, qbuf, u16pad);
  lgk         <<<dim3(16, 64),    dim3(64),  0, stream>>>(x, u16pad, logitbuf);
  xbk         <<<dim3(64, 64),    dim3(64),  0, stream>>>(logitbuf, xT, xbar);
  vk          <<<dim3(8, 4, 4),   dim3(256), 0, stream>>>(xbar, Wkv, attnout);
  spatialf    <<<dim3(4, 64),     dim3(256), 0, stream>>>(attnout, Wout, bout, spatial, rvec);
  // Y[b] = xT[b] @ MT^T * SCALE  (1024x256, K=256)
  gemm128<8,256,256,256,true><<<dim3(8, 2, 64), dim3(256), 0, stream>>>(xT, MT, Ybuf,
                                                                        262144, 0, 262144);
  speck       <<<dim3(1024),      dim3(1024), 0, stream>>>(Ybuf, xT, spatial, rvec);
  bcast       <<<dim3(16384),     dim3(256), 0, stream>>>(rvec, out);
}

// Round 19
// 201.392 us; speedup vs baseline: 1.2535x; 1.0469x over previous
//
#include <hip/hip_runtime.h>
#include <hip/hip_bf16.h>
#include <cstdint>

typedef _Float16 f16;
typedef _Float16 half8 __attribute__((ext_vector_type(8)));
typedef float f32x4 __attribute__((ext_vector_type(4)));

#define SCALE 0.125f

// async global->LDS, 16B per lane, dest = wave-uniform base + lane*16
#define GLL(src, dst) __builtin_amdgcn_global_load_lds( \
    (const __attribute__((address_space(1))) unsigned int*)(src), \
    (__attribute__((address_space(3))) unsigned int*)(dst), 16, 0, 0)

// ---------------- prep: x (64,256,1024) f32 -> xT (64,1024,256) f16 (vectorized both sides) ----
__global__ __launch_bounds__(256) void prep_xT(const float* __restrict__ x, f16* __restrict__ xT) {
  __shared__ f16 tile[64][34];
  int dt = blockIdx.x, nt = blockIdx.y, b = blockIdx.z;
  int t = threadIdx.x;
#pragma unroll
  for (int p = 0; p < 2; ++p) {
    int n = p*32 + (t >> 3), dg = t & 7;
    f32x4 v = *(const f32x4*)(x + ((size_t)b*256 + nt*64 + n)*1024 + dt*32 + dg*4);
    f16* dst = &tile[n][dg*4];
    dst[0] = (f16)v[0]; dst[1] = (f16)v[1]; dst[2] = (f16)v[2]; dst[3] = (f16)v[3];
  }
  __syncthreads();
  {
    int d = t >> 3, ng = t & 7;
    half8 o;
#pragma unroll
    for (int j = 0; j < 8; ++j) o[j] = tile[ng*8 + j][d];
    *(half8*)(xT + ((size_t)b*1024 + dt*32 + d)*256 + nt*64 + ng*8) = o;
  }
}

// ---------------- prep: Wspec (256,768) f32 -> Wspec16 [256][512] f16 (first 512 cols) ----
__global__ __launch_bounds__(256) void prep_Wspec16(const float* __restrict__ W, f16* __restrict__ Wt) {
  int row = blockIdx.x, t = threadIdx.x;
  Wt[(size_t)row*512 + t]       = (f16)W[(size_t)row*768 + t];
  Wt[(size_t)row*512 + 256 + t] = (f16)W[(size_t)row*768 + 256 + t];
}

// ---------------- 128x128x(32*KSTEPS) f16 GEMM (used only for MT = Wk @ Wq^T) ----
template<int KSTEPS, int AST, int BST, int CST, bool SCALEQ>
__global__ __launch_bounds__(256) void gemm128(const f16* __restrict__ Ag, const f16* __restrict__ Bg,
                                               f16* __restrict__ Cg, size_t aB, size_t bB, size_t cB) {
  __shared__ f16 As[2][128*32];
  __shared__ f16 Bs[2][128*32];
  const f16* A = Ag + (size_t)blockIdx.z*aB;
  const f16* B = Bg + (size_t)blockIdx.z*bB;
  f16* C = Cg + (size_t)blockIdx.z*cB;
  int t = threadIdx.x, lane = t & 63, wave = t >> 6;
  int l15 = lane & 15, l4 = lane >> 4;
  int wm = wave & 1, wn = wave >> 1;
  size_t m0 = (size_t)blockIdx.x*128, n0 = (size_t)blockIdx.y*128;
  f32x4 acc[4][4];
#pragma unroll
  for (int i=0;i<4;++i)
#pragma unroll
    for (int j=0;j<4;++j) acc[i][j] = (f32x4){0.f,0.f,0.f,0.f};
  int rowS[2], chS[2];
#pragma unroll
  for (int c=0;c<2;++c) {
    int slot = c*256 + t;
    rowS[c] = slot >> 2;
    chS[c]  = (slot & 3) ^ ((slot >> 3) & 3);
  }
  int pc = (l4 ^ ((l15 >> 1) & 3)) * 8;

  auto STAGE = [&](int buf, int ks) {
    int k0 = ks*32;
#pragma unroll
    for (int c=0;c<2;++c) {
      GLL(A + (m0 + rowS[c])*(size_t)AST + k0 + chS[c]*8, &As[buf][(c*256 + wave*64)*8]);
      GLL(B + (n0 + rowS[c])*(size_t)BST + k0 + chS[c]*8, &Bs[buf][(c*256 + wave*64)*8]);
    }
  };

  STAGE(0, 0);
#pragma unroll 2
  for (int ks = 0; ks < KSTEPS; ++ks) {
    int cur = ks & 1;
    if (ks + 1 < KSTEPS) {
      STAGE(cur ^ 1, ks + 1);
      asm volatile("s_waitcnt vmcnt(4)" ::: "memory");
    } else {
      asm volatile("s_waitcnt vmcnt(0)" ::: "memory");
    }
    __builtin_amdgcn_s_barrier();
    __builtin_amdgcn_sched_barrier(0);
    half8 a[4], bb[4];
    const f16* Af = &As[cur][(wm*64 + l15)*32 + pc];
    const f16* Bf = &Bs[cur][(wn*64 + l15)*32 + pc];
#pragma unroll
    for (int mi=0;mi<4;++mi) a[mi]  = *(const half8*)(Af + mi*16*32);
#pragma unroll
    for (int ni=0;ni<4;++ni) bb[ni] = *(const half8*)(Bf + ni*16*32);
    __builtin_amdgcn_s_setprio(1);
#pragma unroll
    for (int mi=0;mi<4;++mi)
#pragma unroll
      for (int ni=0;ni<4;++ni)
        acc[mi][ni] = __builtin_amdgcn_mfma_f32_16x16x32_f16(a[mi], bb[ni], acc[mi][ni], 0,0,0);
    __builtin_amdgcn_s_setprio(0);
    __builtin_amdgcn_sched_barrier(0);
    __builtin_amdgcn_s_barrier();
  }
  float cscale = SCALEQ ? SCALE : 1.0f;
#pragma unroll
  for (int mi=0;mi<4;++mi)
#pragma unroll
    for (int ni=0;ni<4;++ni)
#pragma unroll
      for (int j=0;j<4;++j) {
        size_t row = m0 + wm*64 + mi*16 + 4*l4 + j;
        size_t col = n0 + wn*64 + ni*16 + l15;
        C[row*CST + col] = (f16)(acc[mi][ni][j] * cscale);
      }
}

// ---------------- qk: q[b][h*64+d] = x_center @ Wq slice (f32); also zeroes attnout slice ----
__global__ __launch_bounds__(256) void qk(const float* __restrict__ x, const float* __restrict__ Wq,
                                          float* __restrict__ qbuf, float* __restrict__ attnout) {
  int b = blockIdx.x, h = blockIdx.y;
  int t = threadIdx.x;
  __shared__ float xc[1024];
  __shared__ float part[4][64];
  if (t < 64) attnout[(size_t)b*512 + h*64 + t] = 0.f;
  const float* xcg = x + ((size_t)b*256 + 128)*1024;
#pragma unroll
  for (int i = 0; i < 4; ++i) xc[t + 256*i] = xcg[t + 256*i];
  __syncthreads();
  int d = t & 63, chunk = t >> 6;
  float s = 0.f;
  const float* wq = Wq + (size_t)(chunk*256)*512 + h*64 + d;
#pragma unroll 8
  for (int c = 0; c < 256; ++c) s += xc[chunk*256 + c] * wq[(size_t)c*512];
  part[chunk][d] = s;
  __syncthreads();
  if (t < 64) qbuf[(size_t)b*512 + h*64 + t] = part[0][t]+part[1][t]+part[2][t]+part[3][t];
}

// ---------------- uk: u16[b][h][d] = sum_j Wkv[d][h*64+j] * q[b][h][j]; also zeroes pad rows ----
__global__ __launch_bounds__(256) void uk(const float* __restrict__ Wkv, const float* __restrict__ qbuf,
                                          f16* __restrict__ u16) {
  int h = blockIdx.x, dc = blockIdx.y;
  int t = threadIdx.x;
  __shared__ float Wk[32][64];
  __shared__ float qT[64][65];
  {
    int j = t & 63, g = t >> 6;
#pragma unroll
    for (int rr = 0; rr < 8; ++rr) {
      int dd = g*8 + rr;
      Wk[dd][j] = Wkv[(size_t)(dc*32 + dd)*1024 + h*64 + j];
    }
#pragma unroll
    for (int rr = 0; rr < 16; ++rr) {
      int bb = g*16 + rr;
      qT[j][bb] = qbuf[(size_t)bb*512 + h*64 + j];
    }
  }
  __syncthreads();
  int b = t & 63, dq = t >> 6;
#pragma unroll
  for (int i = 0; i < 8; ++i) {
    int dd = dq*8 + i;
    float s = 0.f;
#pragma unroll 8
    for (int j = 0; j < 64; ++j) s += qT[j][b] * Wk[dd][j];
    u16[((size_t)b*16 + h)*1024 + dc*32 + dd]       = (f16)s;
    u16[((size_t)b*16 + 8 + h)*1024 + dc*32 + dd]   = (f16)0.f;
  }
}

// ---------------- lgk: logits[b][n][h] = sum_d x[b][n][d] * u16[b][h][d] (MFMA, 1 wave) ----
__global__ __launch_bounds__(64) void lgk(const float* __restrict__ x, const f16* __restrict__ u16,
                                          float* __restrict__ logitbuf) {
  int mt = blockIdx.x, b = blockIdx.y;
  int lane = threadIdx.x, l15 = lane & 15, l4 = lane >> 4;
  const float* Ap = x + ((size_t)b*256 + mt*16 + l15)*1024 + 8*l4;
  const f16* Bp = u16 + ((size_t)b*16 + l15)*1024 + 8*l4;
  f32x4 acc = (f32x4){0.f,0.f,0.f,0.f};
#pragma unroll 8
  for (int ks = 0; ks < 32; ++ks) {
    f32x4 lo = *(const f32x4*)(Ap + ks*32);
    f32x4 hi = *(const f32x4*)(Ap + ks*32 + 4);
    half8 h;
    h[0]=(f16)lo[0]; h[1]=(f16)lo[1]; h[2]=(f16)lo[2]; h[3]=(f16)lo[3];
    h[4]=(f16)hi[0]; h[5]=(f16)hi[1]; h[6]=(f16)hi[2]; h[7]=(f16)hi[3];
    acc = __builtin_amdgcn_mfma_f32_16x16x32_f16(h, *(const half8*)(Bp + ks*32), acc, 0,0,0);
  }
  if (l15 < 8) {
#pragma unroll
    for (int j = 0; j < 4; ++j)
      logitbuf[((size_t)b*256 + mt*16 + 4*l4 + j)*8 + l15] = acc[j];
  }
}

// ---------------- xbk (sm fused): softmax-on-the-fly, xbar = attnW @ xT (MFMA, 1 wave) ----
__global__ __launch_bounds__(64) void xbk(const float* __restrict__ logitbuf, const f16* __restrict__ xT,
                                          f16* __restrict__ xbar) {
  int dt = blockIdx.x, b = blockIdx.y;
  int lane = threadIdx.x, l15 = lane & 15, l4 = lane >> 4;
  const float* lp = logitbuf + (size_t)b*256*8;
  float Z = 0.f;
  if (l15 < 8) {
#pragma unroll 8
    for (int n = l4*64; n < l4*64 + 64; ++n)
      Z += __expf(lp[(size_t)n*8 + l15] * SCALE);
  }
  Z += __shfl_xor(Z, 16);
  Z += __shfl_xor(Z, 32);
  float rZ = (l15 < 8) ? (1.0f / Z) : 0.f;
  const f16* Bp = xT + ((size_t)b*1024 + dt*16 + l15)*256 + 8*l4;
  f32x4 acc = (f32x4){0.f,0.f,0.f,0.f};
#pragma unroll
  for (int ks = 0; ks < 8; ++ks) {
    half8 a;
    if (l15 < 8) {
#pragma unroll
      for (int j = 0; j < 8; ++j) {
        int n = ks*32 + l4*8 + j;
        a[j] = (f16)(__expf(lp[(size_t)n*8 + l15] * SCALE) * rZ);
      }
    } else {
#pragma unroll
      for (int j = 0; j < 8; ++j) a[j] = (f16)0.f;
    }
    acc = __builtin_amdgcn_mfma_f32_16x16x32_f16(a, *(const half8*)(Bp + ks*32), acc, 0,0,0);
  }
  if (l4 < 2) {
#pragma unroll
    for (int j = 0; j < 4; ++j)
      xbar[((size_t)b*8 + 4*l4 + j)*1024 + dt*16 + l15] = (f16)acc[j];
  }
}

// ---------------- vk: attnout[b][h*64+j] += sum_d xbar[b][h][d] * Wkv[d][512+h*64+j] ----
__global__ __launch_bounds__(256) void vk(const f16* __restrict__ xbar, const float* __restrict__ Wkv,
                                          float* __restrict__ attnout) {
  int h = blockIdx.x, dc = blockIdx.y, bc = blockIdx.z;
  int t = threadIdx.x;
  __shared__ float Wv[256][64];
  {
    int j = t & 63, g = t >> 6;
#pragma unroll
    for (int rr = 0; rr < 64; ++rr) {
      int dd = g*64 + rr;
      Wv[dd][j] = Wkv[(size_t)(dc*256 + dd)*1024 + 512 + h*64 + j];
    }
  }
  __syncthreads();
  int j = t & 63, bq = t >> 6;
  float s[4] = {0.f,0.f,0.f,0.f};
  const f16* xp[4];
#pragma unroll
  for (int bl = 0; bl < 4; ++bl)
    xp[bl] = xbar + ((size_t)(bc*16 + bq*4 + bl)*8 + h)*1024 + dc*256;
  for (int d8 = 0; d8 < 32; ++d8) {
    half8 xv[4];
#pragma unroll
    for (int bl = 0; bl < 4; ++bl) xv[bl] = *(const half8*)(xp[bl] + d8*8);
#pragma unroll
    for (int i = 0; i < 8; ++i) {
      float w = Wv[d8*8 + i][j];
#pragma unroll
      for (int bl = 0; bl < 4; ++bl) s[bl] += (float)xv[bl][i] * w;
    }
  }
#pragma unroll
  for (int bl = 0; bl < 4; ++bl)
    atomicAdd(&attnout[(size_t)(bc*16 + bq*4 + bl)*512 + h*64 + j], s[bl]);
}

// ---------------- spatialf: spatial = attnout @ Wout + bout; also zeroes rvec slice ----
__global__ __launch_bounds__(256) void spatialf(const float* __restrict__ attnout, const float* __restrict__ Wout,
                                                const float* __restrict__ bout, float* __restrict__ spatial,
                                                float* __restrict__ rvec) {
  int ec = blockIdx.x, b = blockIdx.y;
  int t = threadIdx.x;
  __shared__ float ao[512];
  rvec[(size_t)b*1024 + ec*256 + t] = 0.f;
  ao[t]       = attnout[(size_t)b*512 + t];
  ao[t + 256] = attnout[(size_t)b*512 + 256 + t];
  __syncthreads();
  int e = ec*256 + t;
  float a0 = bout[e], a1 = 0.f;
#pragma unroll 8
  for (int i = 0; i < 512; i += 2) {
    a0 += ao[i]     * Wout[(size_t)i*1024 + e];
    a1 += ao[i + 1] * Wout[(size_t)(i + 1)*1024 + e];
  }
  spatial[(size_t)b*1024 + e] = a0 + a1;
}

// ---------------- spec v14: Y-GEMM fused via MT-in-LDS (fixes v12's direct-global MT reads).
// Prologue: GLL xT-tile->As + MT->Bs; Y = xT@MT*SCALE from LDS/LDS; Y overwrites As (swizzled);
// Bs then reused as the per-wave B ring. K-loop = proven v11 (16 waves @4/SIMD, counted vmcnt).
__global__ __launch_bounds__(1024, 4) void speck(const f16* __restrict__ MT, const f16* __restrict__ xT,
                                                 const float* __restrict__ spatial, float* __restrict__ r) {
  __shared__ __attribute__((aligned(16))) char smem[163840];
  f16* As = (f16*)smem;                       // 32 KB: A tile (xT, then Y), row-swizzled
  f16* Bs = (f16*)(smem + 32768);             // 128 KB: MT (prologue), then B ring
  float* sz   = (float*)smem;                 // post-loop alias of As (fenced)
  float* zfin = (float*)(smem + 4096);
  int bid = blockIdx.x;
  int xcd = bid & 7, q = bid >> 3;
  int b = xcd*8 + (q >> 4);                   // batch pinned to one XCD
  int iblk = q & 15;
  int t = threadIdx.x, lane = t & 63, wave = t >> 6;
  int l15 = lane & 15, l4 = lane >> 4;
  const f16* xTb = xT + (size_t)b*262144;
  int i0 = iblk*64;
  int axor = l15 & 7;

  // ---- stage xT A-tile into As (2 GLL/wave, 3-bit row XOR on SOURCE slot) ----
#pragma unroll
  for (int g = 0; g < 2; ++g) {
    int u = (wave*2 + g)*64 + lane;
    int rA = u >> 5, v = u & 31;
    int s = v ^ (rA & 7);
    GLL(xTb + (size_t)(i0 + rA)*256 + (s >> 2)*32 + (s & 3)*8, As + ((wave*2 + g)*64)*8);
  }
  // ---- stage MT (256x256 f16 = 128 KB) into Bs (8 GLL/thread, same swizzle) ----
#pragma unroll
  for (int g = 0; g < 8; ++g) {
    int ub = g*1024 + wave*64;
    int u = ub + lane;
    int row = u >> 5, v = u & 31;
    int s = v ^ (row & 7);
    GLL(MT + (size_t)row*256 + (s >> 2)*32 + (s & 3)*8, Bs + ub*8);
  }
  asm volatile("s_waitcnt vmcnt(0)" ::: "memory");
  __builtin_amdgcn_s_barrier();               // xT tile + MT visible in LDS
  __builtin_amdgcn_sched_barrier(0);

  // ---- Y-compute: wave (w&3) rows, (w>>2) cols; both operands from swizzled LDS ----
  int r0 = (wave & 3)*16, c0 = (wave >> 2)*64;
  f32x4 accy[4];
#pragma unroll
  for (int ci = 0; ci < 4; ++ci) accy[ci] = (f32x4){0.f,0.f,0.f,0.f};
#pragma unroll
  for (int ks = 0; ks < 8; ++ks) {
    int ls = ks*4 + l4;
    half8 ax = *(const half8*)(As + (r0 + l15)*256 + ((ls ^ axor)*8));
#pragma unroll
    for (int ci = 0; ci < 4; ++ci) {
      int c = c0 + ci*16 + l15;
      half8 bmt = *(const half8*)(Bs + c*256 + ((ls ^ (c & 7))*8));
      accy[ci] = __builtin_amdgcn_mfma_f32_16x16x32_f16(ax, bmt, accy[ci], 0,0,0);
    }
  }
  __builtin_amdgcn_sched_barrier(0);
  __builtin_amdgcn_s_barrier();               // all xT/MT LDS reads complete

  // ---- B ring staging may now overwrite Bs; Y overwrites As (swizzled writes) ----
  auto STAGE_B = [&](int slot, int ks) {
    int k0 = ks*32;
#pragma unroll
    for (int c = 0; c < 4; ++c) {
      int u2 = c*64 + lane;
      int row = u2 >> 2, pchk = u2 & 3;
      int ch = pchk ^ (((row & 15) >> 1) & 3);
      GLL(xTb + (size_t)(wave*64 + row)*256 + k0 + ch*8,
          Bs + ((wave*2 + slot)*256 + c*64)*8);
    }
  };
  STAGE_B(0, 0);
  STAGE_B(1, 1);
#pragma unroll
  for (int ci = 0; ci < 4; ++ci) {
    int col = c0 + ci*16 + l15;
    int ls2 = col >> 3, off = col & 7;
#pragma unroll
    for (int jj = 0; jj < 4; ++jj) {
      int row = r0 + 4*l4 + jj;
      As[row*256 + ((ls2 ^ (row & 7))*8) + off] = (f16)(accy[ci][jj] * SCALE);
    }
  }
  asm volatile("s_waitcnt lgkmcnt(0)" ::: "memory");
  __builtin_amdgcn_sched_barrier(0);
  __builtin_amdgcn_s_barrier();               // Y visible to all waves; B0/B1 still in flight

  f32x4 acc[4][4];
#pragma unroll
  for (int mi=0;mi<4;++mi)
#pragma unroll
    for (int ni=0;ni<4;++ni) acc[mi][ni] = (f32x4){0.f,0.f,0.f,0.f};
  int pc = (l4 ^ ((l15 >> 1) & 3)) * 8;

  // ---- v11 K-loop: free-running waves, per-wave counted vmcnt ----
#pragma unroll
  for (int ks = 0; ks < 8; ++ks) {
    int slot = ks & 1;
    if (ks < 7) asm volatile("s_waitcnt vmcnt(4)" ::: "memory");
    else        asm volatile("s_waitcnt vmcnt(0)" ::: "memory");
    __builtin_amdgcn_sched_barrier(0);
    half8 a[4], bb[4];
    const f16* Bbase = Bs + (wave*2 + slot)*2048;
    int physA = ((ks*4 + l4) ^ axor)*8;
#pragma unroll
    for (int mi = 0; mi < 4; ++mi) a[mi]  = *(const half8*)(As + (mi*16 + l15)*256 + physA);
#pragma unroll
    for (int ni = 0; ni < 4; ++ni) bb[ni] = *(const half8*)(Bbase + (ni*16 + l15)*32 + pc);
    asm volatile("s_waitcnt lgkmcnt(0)" ::: "memory");
    __builtin_amdgcn_sched_barrier(0);
    if (ks < 6) STAGE_B(slot, ks + 2);
    __builtin_amdgcn_s_setprio(1);
#pragma unroll
    for (int ni = 0; ni < 4; ++ni)
#pragma unroll
      for (int mi = 0; mi < 4; ++mi)
        acc[mi][ni] = __builtin_amdgcn_mfma_f32_16x16x32_f16(a[mi], bb[ni], acc[mi][ni], 0,0,0);
    __builtin_amdgcn_s_setprio(0);
    __builtin_amdgcn_sched_barrier(0);
  }
  // ---- no-max softmax; wave-local row partials in regs; sz aliases As after full barrier ----
  float zr[4][4];
#pragma unroll
  for (int mi=0;mi<4;++mi)
#pragma unroll
    for (int jj=0;jj<4;++jj) {
      float s = 0.f;
#pragma unroll
      for (int ni=0;ni<4;++ni) {
        float e = __expf(acc[mi][ni][jj]);
        acc[mi][ni][jj] = e;
        s += e;
      }
#pragma unroll
      for (int o=1;o<16;o<<=1) s += __shfl_xor(s, o);
      zr[mi][jj] = s;
    }
  __syncthreads();
  if (l15 == 0) {
#pragma unroll
    for (int mi=0;mi<4;++mi)
#pragma unroll
      for (int jj=0;jj<4;++jj) sz[(mi*16 + 4*l4 + jj)*16 + wave] = zr[mi][jj];
  }
  __syncthreads();
  {
    float v = sz[t];
#pragma unroll
    for (int o=1;o<16;o<<=1) v += __shfl_xor(v, o);
    if ((t & 15) == 0) zfin[t >> 4] = v;
  }
  __syncthreads();
  float f[4][4];
#pragma unroll
  for (int mi=0;mi<4;++mi)
#pragma unroll
    for (int jj=0;jj<4;++jj) {
      int row = mi*16 + 4*l4 + jj;
      f[mi][jj] = spatial[(size_t)b*1024 + i0 + row] / zfin[row];
    }
  float* rb = r + (size_t)b*1024;
#pragma unroll
  for (int ni=0;ni<4;++ni) {
    float v = 0.f;
#pragma unroll
    for (int mi=0;mi<4;++mi)
#pragma unroll
      for (int jj=0;jj<4;++jj) v += f[mi][jj]*acc[mi][ni][jj];
    v += __shfl_xor(v, 16);
    v += __shfl_xor(v, 32);
    if (l4 == 0) atomicAdd(rb + wave*64 + ni*16 + l15, v);
  }
}

// ---------------- broadcast: out[b,n,:] = r[b,:] ----------------
__global__ __launch_bounds__(256) void bcast(const float* __restrict__ r, float* __restrict__ out) {
  size_t row = blockIdx.x;
  int b = (int)(row >> 8);
  f32x4 v = *(const f32x4*)(r + (size_t)b*1024 + threadIdx.x*4);
  *(f32x4*)(out + row*1024 + (size_t)threadIdx.x*4) = v;
}

extern "C" void kernel_launch(void* const* d_in, const int* in_sizes, int n_in,
                              void* d_out, int out_size, void* d_ws, size_t ws_size,
                              hipStream_t stream) {
  const float* x     = (const float*)d_in[0];
  const float* Wq    = (const float*)d_in[1];
  const float* Wkv   = (const float*)d_in[2];
  const float* Wout  = (const float*)d_in[3];
  const float* bout  = (const float*)d_in[4];
  const float* Wspec = (const float*)d_in[5];
  float* out = (float*)d_out;
  char* ws = (char*)d_ws;
  // workspace aliases (stream-ordered): attn-chain scratch at ws+0..6M (u16pad@0,
  // logitbuf@2M, xbar@3M, qbuf@5.25M); MT@32M; xT@64M; Wspec16/attnout/spatial/rvec @98M+
  f16*   u16pad   = (f16*)(ws);
  float* logitbuf = (float*)(ws + 2097152);
  f16*   xbar     = (f16*)(ws + 3145728);
  float* qbuf     = (float*)(ws + 5242880);
  f16*   MT       = (f16*)(ws + 33554432);
  f16*   xT       = (f16*)(ws + 67108864);
  f16*   Wspec16  = (f16*)(ws + 102760448);
  float* attnout  = (float*)(ws + 103022592);
  float* spatial  = (float*)(ws + 103153664);
  float* rvec     = (float*)(ws + 103415808);
  (void)in_sizes; (void)n_in; (void)out_size; (void)ws_size;

  prep_xT     <<<dim3(32, 4, 64), dim3(256), 0, stream>>>(x, xT);
  prep_Wspec16<<<dim3(256),       dim3(256), 0, stream>>>(Wspec, Wspec16);
  // MT[m][n] = sum_j Wk[m][j]*Wq[n][j]  (256x256)
  gemm128<8,512,512,256,false><<<dim3(2, 2, 1), dim3(256), 0, stream>>>(Wspec16 + 256, Wspec16, MT, 0, 0, 0);
  qk          <<<dim3(64, 8),     dim3(256), 0, stream>>>(x, Wq, qbuf, attnout);
  uk          <<<dim3(8, 32),     dim3(256), 0, stream>>>(Wkv, qbuf, u16pad);
  lgk         <<<dim3(16, 64),    dim3(64),  0, stream>>>(x, u16pad, logitbuf);
  xbk         <<<dim3(64, 64),    dim3(64),  0, stream>>>(logitbuf, xT, xbar);
  vk          <<<dim3(8, 4, 4),   dim3(256), 0, stream>>>(xbar, Wkv, attnout);
  spatialf    <<<dim3(4, 64),     dim3(256), 0, stream>>>(attnout, Wout, bout, spatial, rvec);
  speck       <<<dim3(1024),      dim3(1024), 0, stream>>>(MT, xT, spatial, rvec);
  bcast       <<<dim3(16384),     dim3(256), 0, stream>>>(rvec, out);
}

// Round 20
// 198.866 us; speedup vs baseline: 1.2694x; 1.0127x over previous
//
#include <hip/hip_runtime.h>
#include <hip/hip_bf16.h>
#include <cstdint>

typedef _Float16 f16;
typedef _Float16 half8 __attribute__((ext_vector_type(8)));
typedef float f32x4 __attribute__((ext_vector_type(4)));

#define SCALE 0.125f

// async global->LDS, 16B per lane, dest = wave-uniform base + lane*16
#define GLL(src, dst) __builtin_amdgcn_global_load_lds( \
    (const __attribute__((address_space(1))) unsigned int*)(src), \
    (__attribute__((address_space(3))) unsigned int*)(dst), 16, 0, 0)

// ---------------- prep: x (64,256,1024) f32 -> xT (64,1024,256) f16 (vectorized both sides) ----
__global__ __launch_bounds__(256) void prep_xT(const float* __restrict__ x, f16* __restrict__ xT) {
  __shared__ f16 tile[64][34];
  int dt = blockIdx.x, nt = blockIdx.y, b = blockIdx.z;
  int t = threadIdx.x;
#pragma unroll
  for (int p = 0; p < 2; ++p) {
    int n = p*32 + (t >> 3), dg = t & 7;
    f32x4 v = *(const f32x4*)(x + ((size_t)b*256 + nt*64 + n)*1024 + dt*32 + dg*4);
    f16* dst = &tile[n][dg*4];
    dst[0] = (f16)v[0]; dst[1] = (f16)v[1]; dst[2] = (f16)v[2]; dst[3] = (f16)v[3];
  }
  __syncthreads();
  {
    int d = t >> 3, ng = t & 7;
    half8 o;
#pragma unroll
    for (int j = 0; j < 8; ++j) o[j] = tile[ng*8 + j][d];
    *(half8*)(xT + ((size_t)b*1024 + dt*32 + d)*256 + nt*64 + ng*8) = o;
  }
}

// ---------------- prep: Wspec (256,768) f32 -> Wspec16 [256][512] f16 (first 512 cols) ----
__global__ __launch_bounds__(256) void prep_Wspec16(const float* __restrict__ W, f16* __restrict__ Wt) {
  int row = blockIdx.x, t = threadIdx.x;
  Wt[(size_t)row*512 + t]       = (f16)W[(size_t)row*768 + t];
  Wt[(size_t)row*512 + 256 + t] = (f16)W[(size_t)row*768 + 256 + t];
}

// ---------------- 128x128x(32*KSTEPS) f16 GEMM (used only for MT = Wk @ Wq^T) ----
template<int KSTEPS, int AST, int BST, int CST, bool SCALEQ>
__global__ __launch_bounds__(256) void gemm128(const f16* __restrict__ Ag, const f16* __restrict__ Bg,
                                               f16* __restrict__ Cg, size_t aB, size_t bB, size_t cB) {
  __shared__ f16 As[2][128*32];
  __shared__ f16 Bs[2][128*32];
  const f16* A = Ag + (size_t)blockIdx.z*aB;
  const f16* B = Bg + (size_t)blockIdx.z*bB;
  f16* C = Cg + (size_t)blockIdx.z*cB;
  int t = threadIdx.x, lane = t & 63, wave = t >> 6;
  int l15 = lane & 15, l4 = lane >> 4;
  int wm = wave & 1, wn = wave >> 1;
  size_t m0 = (size_t)blockIdx.x*128, n0 = (size_t)blockIdx.y*128;
  f32x4 acc[4][4];
#pragma unroll
  for (int i=0;i<4;++i)
#pragma unroll
    for (int j=0;j<4;++j) acc[i][j] = (f32x4){0.f,0.f,0.f,0.f};
  int rowS[2], chS[2];
#pragma unroll
  for (int c=0;c<2;++c) {
    int slot = c*256 + t;
    rowS[c] = slot >> 2;
    chS[c]  = (slot & 3) ^ ((slot >> 3) & 3);
  }
  int pc = (l4 ^ ((l15 >> 1) & 3)) * 8;

  auto STAGE = [&](int buf, int ks) {
    int k0 = ks*32;
#pragma unroll
    for (int c=0;c<2;++c) {
      GLL(A + (m0 + rowS[c])*(size_t)AST + k0 + chS[c]*8, &As[buf][(c*256 + wave*64)*8]);
      GLL(B + (n0 + rowS[c])*(size_t)BST + k0 + chS[c]*8, &Bs[buf][(c*256 + wave*64)*8]);
    }
  };

  STAGE(0, 0);
#pragma unroll 2
  for (int ks = 0; ks < KSTEPS; ++ks) {
    int cur = ks & 1;
    if (ks + 1 < KSTEPS) {
      STAGE(cur ^ 1, ks + 1);
      asm volatile("s_waitcnt vmcnt(4)" ::: "memory");
    } else {
      asm volatile("s_waitcnt vmcnt(0)" ::: "memory");
    }
    __builtin_amdgcn_s_barrier();
    __builtin_amdgcn_sched_barrier(0);
    half8 a[4], bb[4];
    const f16* Af = &As[cur][(wm*64 + l15)*32 + pc];
    const f16* Bf = &Bs[cur][(wn*64 + l15)*32 + pc];
#pragma unroll
    for (int mi=0;mi<4;++mi) a[mi]  = *(const half8*)(Af + mi*16*32);
#pragma unroll
    for (int ni=0;ni<4;++ni) bb[ni] = *(const half8*)(Bf + ni*16*32);
    __builtin_amdgcn_s_setprio(1);
#pragma unroll
    for (int mi=0;mi<4;++mi)
#pragma unroll
      for (int ni=0;ni<4;++ni)
        acc[mi][ni] = __builtin_amdgcn_mfma_f32_16x16x32_f16(a[mi], bb[ni], acc[mi][ni], 0,0,0);
    __builtin_amdgcn_s_setprio(0);
    __builtin_amdgcn_sched_barrier(0);
    __builtin_amdgcn_s_barrier();
  }
  float cscale = SCALEQ ? SCALE : 1.0f;
#pragma unroll
  for (int mi=0;mi<4;++mi)
#pragma unroll
    for (int ni=0;ni<4;++ni)
#pragma unroll
      for (int j=0;j<4;++j) {
        size_t row = m0 + wm*64 + mi*16 + 4*l4 + j;
        size_t col = n0 + wn*64 + ni*16 + l15;
        C[row*CST + col] = (f16)(acc[mi][ni][j] * cscale);
      }
}

// ---------------- qk: q[b][h*64+d] = x_center @ Wq slice (f32); also zeroes attnout slice ----
__global__ __launch_bounds__(256) void qk(const float* __restrict__ x, const float* __restrict__ Wq,
                                          float* __restrict__ qbuf, float* __restrict__ attnout) {
  int b = blockIdx.x, h = blockIdx.y;
  int t = threadIdx.x;
  __shared__ float xc[1024];
  __shared__ float part[4][64];
  if (t < 64) attnout[(size_t)b*512 + h*64 + t] = 0.f;
  const float* xcg = x + ((size_t)b*256 + 128)*1024;
#pragma unroll
  for (int i = 0; i < 4; ++i) xc[t + 256*i] = xcg[t + 256*i];
  __syncthreads();
  int d = t & 63, chunk = t >> 6;
  float s = 0.f;
  const float* wq = Wq + (size_t)(chunk*256)*512 + h*64 + d;
#pragma unroll 8
  for (int c = 0; c < 256; ++c) s += xc[chunk*256 + c] * wq[(size_t)c*512];
  part[chunk][d] = s;
  __syncthreads();
  if (t < 64) qbuf[(size_t)b*512 + h*64 + t] = part[0][t]+part[1][t]+part[2][t]+part[3][t];
}

// ---------------- uk: u16[b][h][d] = sum_j Wkv[d][h*64+j] * q[b][h][j]; also zeroes pad rows ----
__global__ __launch_bounds__(256) void uk(const float* __restrict__ Wkv, const float* __restrict__ qbuf,
                                          f16* __restrict__ u16) {
  int h = blockIdx.x, dc = blockIdx.y;
  int t = threadIdx.x;
  __shared__ float Wk[32][64];
  __shared__ float qT[64][65];
  {
    int j = t & 63, g = t >> 6;
#pragma unroll
    for (int rr = 0; rr < 8; ++rr) {
      int dd = g*8 + rr;
      Wk[dd][j] = Wkv[(size_t)(dc*32 + dd)*1024 + h*64 + j];
    }
#pragma unroll
    for (int rr = 0; rr < 16; ++rr) {
      int bb = g*16 + rr;
      qT[j][bb] = qbuf[(size_t)bb*512 + h*64 + j];
    }
  }
  __syncthreads();
  int b = t & 63, dq = t >> 6;
#pragma unroll
  for (int i = 0; i < 8; ++i) {
    int dd = dq*8 + i;
    float s = 0.f;
#pragma unroll 8
    for (int j = 0; j < 64; ++j) s += qT[j][b] * Wk[dd][j];
    u16[((size_t)b*16 + h)*1024 + dc*32 + dd]       = (f16)s;
    u16[((size_t)b*16 + 8 + h)*1024 + dc*32 + dd]   = (f16)0.f;
  }
}

// ---------------- lgk: logits[b][n][h] = sum_d x[b][n][d] * u16[b][h][d] (MFMA, 1 wave) ----
__global__ __launch_bounds__(64) void lgk(const float* __restrict__ x, const f16* __restrict__ u16,
                                          float* __restrict__ logitbuf) {
  int mt = blockIdx.x, b = blockIdx.y;
  int lane = threadIdx.x, l15 = lane & 15, l4 = lane >> 4;
  const float* Ap = x + ((size_t)b*256 + mt*16 + l15)*1024 + 8*l4;
  const f16* Bp = u16 + ((size_t)b*16 + l15)*1024 + 8*l4;
  f32x4 acc = (f32x4){0.f,0.f,0.f,0.f};
#pragma unroll 8
  for (int ks = 0; ks < 32; ++ks) {
    f32x4 lo = *(const f32x4*)(Ap + ks*32);
    f32x4 hi = *(const f32x4*)(Ap + ks*32 + 4);
    half8 h;
    h[0]=(f16)lo[0]; h[1]=(f16)lo[1]; h[2]=(f16)lo[2]; h[3]=(f16)lo[3];
    h[4]=(f16)hi[0]; h[5]=(f16)hi[1]; h[6]=(f16)hi[2]; h[7]=(f16)hi[3];
    acc = __builtin_amdgcn_mfma_f32_16x16x32_f16(h, *(const half8*)(Bp + ks*32), acc, 0,0,0);
  }
  if (l15 < 8) {
#pragma unroll
    for (int j = 0; j < 4; ++j)
      logitbuf[((size_t)b*256 + mt*16 + 4*l4 + j)*8 + l15] = acc[j];
  }
}

// ---------------- xbk (sm fused): softmax-on-the-fly, xbar = attnW @ xT (MFMA, 1 wave) ----
__global__ __launch_bounds__(64) void xbk(const float* __restrict__ logitbuf, const f16* __restrict__ xT,
                                          f16* __restrict__ xbar) {
  int dt = blockIdx.x, b = blockIdx.y;
  int lane = threadIdx.x, l15 = lane & 15, l4 = lane >> 4;
  const float* lp = logitbuf + (size_t)b*256*8;
  float Z = 0.f;
  if (l15 < 8) {
#pragma unroll 8
    for (int n = l4*64; n < l4*64 + 64; ++n)
      Z += __expf(lp[(size_t)n*8 + l15] * SCALE);
  }
  Z += __shfl_xor(Z, 16);
  Z += __shfl_xor(Z, 32);
  float rZ = (l15 < 8) ? (1.0f / Z) : 0.f;
  const f16* Bp = xT + ((size_t)b*1024 + dt*16 + l15)*256 + 8*l4;
  f32x4 acc = (f32x4){0.f,0.f,0.f,0.f};
#pragma unroll
  for (int ks = 0; ks < 8; ++ks) {
    half8 a;
    if (l15 < 8) {
#pragma unroll
      for (int j = 0; j < 8; ++j) {
        int n = ks*32 + l4*8 + j;
        a[j] = (f16)(__expf(lp[(size_t)n*8 + l15] * SCALE) * rZ);
      }
    } else {
#pragma unroll
      for (int j = 0; j < 8; ++j) a[j] = (f16)0.f;
    }
    acc = __builtin_amdgcn_mfma_f32_16x16x32_f16(a, *(const half8*)(Bp + ks*32), acc, 0,0,0);
  }
  if (l4 < 2) {
#pragma unroll
    for (int j = 0; j < 4; ++j)
      xbar[((size_t)b*8 + 4*l4 + j)*1024 + dt*16 + l15] = (f16)acc[j];
  }
}

// ---------------- vk v2: grid (8 h, 4 dc, 8 bc) -> 256 blocks (full CU coverage);
// each block does 8 batches: attnout[b][h*64+j] += sum_d xbar[b][h][d]*Wkv[d][512+h*64+j] ----
__global__ __launch_bounds__(256) void vk(const f16* __restrict__ xbar, const float* __restrict__ Wkv,
                                          float* __restrict__ attnout) {
  int h = blockIdx.x, dc = blockIdx.y, bc = blockIdx.z;
  int t = threadIdx.x;
  __shared__ float Wv[256][64];
  {
    int j = t & 63, g = t >> 6;
#pragma unroll
    for (int rr = 0; rr < 64; ++rr) {
      int dd = g*64 + rr;
      Wv[dd][j] = Wkv[(size_t)(dc*256 + dd)*1024 + 512 + h*64 + j];
    }
  }
  __syncthreads();
  int j = t & 63, bq = t >> 6;
  float s[2] = {0.f, 0.f};
  const f16* xp[2];
#pragma unroll
  for (int bl = 0; bl < 2; ++bl)
    xp[bl] = xbar + ((size_t)(bc*8 + bq*2 + bl)*8 + h)*1024 + dc*256;
  for (int d8 = 0; d8 < 32; ++d8) {
    half8 xv[2];
#pragma unroll
    for (int bl = 0; bl < 2; ++bl) xv[bl] = *(const half8*)(xp[bl] + d8*8);
#pragma unroll
    for (int i = 0; i < 8; ++i) {
      float w = Wv[d8*8 + i][j];
#pragma unroll
      for (int bl = 0; bl < 2; ++bl) s[bl] += (float)xv[bl][i] * w;
    }
  }
#pragma unroll
  for (int bl = 0; bl < 2; ++bl)
    atomicAdd(&attnout[(size_t)(bc*8 + bq*2 + bl)*512 + h*64 + j], s[bl]);
}

// ---------------- spatialf: spatial = attnout @ Wout + bout; also zeroes rvec slice ----
__global__ __launch_bounds__(256) void spatialf(const float* __restrict__ attnout, const float* __restrict__ Wout,
                                                const float* __restrict__ bout, float* __restrict__ spatial,
                                                float* __restrict__ rvec) {
  int ec = blockIdx.x, b = blockIdx.y;
  int t = threadIdx.x;
  __shared__ float ao[512];
  rvec[(size_t)b*1024 + ec*256 + t] = 0.f;
  ao[t]       = attnout[(size_t)b*512 + t];
  ao[t + 256] = attnout[(size_t)b*512 + 256 + t];
  __syncthreads();
  int e = ec*256 + t;
  float a0 = bout[e], a1 = 0.f;
#pragma unroll 8
  for (int i = 0; i < 512; i += 2) {
    a0 += ao[i]     * Wout[(size_t)i*1024 + e];
    a1 += ao[i + 1] * Wout[(size_t)(i + 1)*1024 + e];
  }
  spatial[(size_t)b*1024 + e] = a0 + a1;
}

// ---------------- spec v14: Y-GEMM fused via MT-in-LDS; v11 K-loop (16 waves @4/SIMD) ----
__global__ __launch_bounds__(1024, 4) void speck(const f16* __restrict__ MT, const f16* __restrict__ xT,
                                                 const float* __restrict__ spatial, float* __restrict__ r) {
  __shared__ __attribute__((aligned(16))) char smem[163840];
  f16* As = (f16*)smem;                       // 32 KB: A tile (xT, then Y), row-swizzled
  f16* Bs = (f16*)(smem + 32768);             // 128 KB: MT (prologue), then B ring
  float* sz   = (float*)smem;                 // post-loop alias of As (fenced)
  float* zfin = (float*)(smem + 4096);
  int bid = blockIdx.x;
  int xcd = bid & 7, q = bid >> 3;
  int b = xcd*8 + (q >> 4);                   // batch pinned to one XCD
  int iblk = q & 15;
  int t = threadIdx.x, lane = t & 63, wave = t >> 6;
  int l15 = lane & 15, l4 = lane >> 4;
  const f16* xTb = xT + (size_t)b*262144;
  int i0 = iblk*64;
  int axor = l15 & 7;

  // ---- stage xT A-tile into As (2 GLL/wave, 3-bit row XOR on SOURCE slot) ----
#pragma unroll
  for (int g = 0; g < 2; ++g) {
    int u = (wave*2 + g)*64 + lane;
    int rA = u >> 5, v = u & 31;
    int s = v ^ (rA & 7);
    GLL(xTb + (size_t)(i0 + rA)*256 + (s >> 2)*32 + (s & 3)*8, As + ((wave*2 + g)*64)*8);
  }
  // ---- stage MT (256x256 f16 = 128 KB) into Bs (8 GLL/thread, same swizzle) ----
#pragma unroll
  for (int g = 0; g < 8; ++g) {
    int ub = g*1024 + wave*64;
    int u = ub + lane;
    int row = u >> 5, v = u & 31;
    int s = v ^ (row & 7);
    GLL(MT + (size_t)row*256 + (s >> 2)*32 + (s & 3)*8, Bs + ub*8);
  }
  asm volatile("s_waitcnt vmcnt(0)" ::: "memory");
  __builtin_amdgcn_s_barrier();
  __builtin_amdgcn_sched_barrier(0);

  // ---- Y-compute: wave (w&3) rows, (w>>2) cols; both operands from swizzled LDS ----
  int r0 = (wave & 3)*16, c0 = (wave >> 2)*64;
  f32x4 accy[4];
#pragma unroll
  for (int ci = 0; ci < 4; ++ci) accy[ci] = (f32x4){0.f,0.f,0.f,0.f};
#pragma unroll
  for (int ks = 0; ks < 8; ++ks) {
    int ls = ks*4 + l4;
    half8 ax = *(const half8*)(As + (r0 + l15)*256 + ((ls ^ axor)*8));
#pragma unroll
    for (int ci = 0; ci < 4; ++ci) {
      int c = c0 + ci*16 + l15;
      half8 bmt = *(const half8*)(Bs + c*256 + ((ls ^ (c & 7))*8));
      accy[ci] = __builtin_amdgcn_mfma_f32_16x16x32_f16(ax, bmt, accy[ci], 0,0,0);
    }
  }
  __builtin_amdgcn_sched_barrier(0);
  __builtin_amdgcn_s_barrier();

  // ---- B ring staging may now overwrite Bs; Y overwrites As (swizzled writes) ----
  auto STAGE_B = [&](int slot, int ks) {
    int k0 = ks*32;
#pragma unroll
    for (int c = 0; c < 4; ++c) {
      int u2 = c*64 + lane;
      int row = u2 >> 2, pchk = u2 & 3;
      int ch = pchk ^ (((row & 15) >> 1) & 3);
      GLL(xTb + (size_t)(wave*64 + row)*256 + k0 + ch*8,
          Bs + ((wave*2 + slot)*256 + c*64)*8);
    }
  };
  STAGE_B(0, 0);
  STAGE_B(1, 1);
#pragma unroll
  for (int ci = 0; ci < 4; ++ci) {
    int col = c0 + ci*16 + l15;
    int ls2 = col >> 3, off = col & 7;
#pragma unroll
    for (int jj = 0; jj < 4; ++jj) {
      int row = r0 + 4*l4 + jj;
      As[row*256 + ((ls2 ^ (row & 7))*8) + off] = (f16)(accy[ci][jj] * SCALE);
    }
  }
  asm volatile("s_waitcnt lgkmcnt(0)" ::: "memory");
  __builtin_amdgcn_sched_barrier(0);
  __builtin_amdgcn_s_barrier();               // Y visible; B0/B1 still in flight

  f32x4 acc[4][4];
#pragma unroll
  for (int mi=0;mi<4;++mi)
#pragma unroll
    for (int ni=0;ni<4;++ni) acc[mi][ni] = (f32x4){0.f,0.f,0.f,0.f};
  int pc = (l4 ^ ((l15 >> 1) & 3)) * 8;

  // ---- v11 K-loop: free-running waves, per-wave counted vmcnt ----
#pragma unroll
  for (int ks = 0; ks < 8; ++ks) {
    int slot = ks & 1;
    if (ks < 7) asm volatile("s_waitcnt vmcnt(4)" ::: "memory");
    else        asm volatile("s_waitcnt vmcnt(0)" ::: "memory");
    __builtin_amdgcn_sched_barrier(0);
    half8 a[4], bb[4];
    const f16* Bbase = Bs + (wave*2 + slot)*2048;
    int physA = ((ks*4 + l4) ^ axor)*8;
#pragma unroll
    for (int mi = 0; mi < 4; ++mi) a[mi]  = *(const half8*)(As + (mi*16 + l15)*256 + physA);
#pragma unroll
    for (int ni = 0; ni < 4; ++ni) bb[ni] = *(const half8*)(Bbase + (ni*16 + l15)*32 + pc);
    asm volatile("s_waitcnt lgkmcnt(0)" ::: "memory");
    __builtin_amdgcn_sched_barrier(0);
    if (ks < 6) STAGE_B(slot, ks + 2);
    __builtin_amdgcn_s_setprio(1);
#pragma unroll
    for (int ni = 0; ni < 4; ++ni)
#pragma unroll
      for (int mi = 0; mi < 4; ++mi)
        acc[mi][ni] = __builtin_amdgcn_mfma_f32_16x16x32_f16(a[mi], bb[ni], acc[mi][ni], 0,0,0);
    __builtin_amdgcn_s_setprio(0);
    __builtin_amdgcn_sched_barrier(0);
  }
  // ---- no-max softmax; wave-local row partials in regs; sz aliases As after full barrier ----
  float zr[4][4];
#pragma unroll
  for (int mi=0;mi<4;++mi)
#pragma unroll
    for (int jj=0;jj<4;++jj) {
      float s = 0.f;
#pragma unroll
      for (int ni=0;ni<4;++ni) {
        float e = __expf(acc[mi][ni][jj]);
        acc[mi][ni][jj] = e;
        s += e;
      }
#pragma unroll
      for (int o=1;o<16;o<<=1) s += __shfl_xor(s, o);
      zr[mi][jj] = s;
    }
  __syncthreads();
  if (l15 == 0) {
#pragma unroll
    for (int mi=0;mi<4;++mi)
#pragma unroll
      for (int jj=0;jj<4;++jj) sz[(mi*16 + 4*l4 + jj)*16 + wave] = zr[mi][jj];
  }
  __syncthreads();
  {
    float v = sz[t];
#pragma unroll
    for (int o=1;o<16;o<<=1) v += __shfl_xor(v, o);
    if ((t & 15) == 0) zfin[t >> 4] = v;
  }
  __syncthreads();
  float f[4][4];
#pragma unroll
  for (int mi=0;mi<4;++mi)
#pragma unroll
    for (int jj=0;jj<4;++jj) {
      int row = mi*16 + 4*l4 + jj;
      f[mi][jj] = spatial[(size_t)b*1024 + i0 + row] / zfin[row];
    }
  float* rb = r + (size_t)b*1024;
#pragma unroll
  for (int ni=0;ni<4;++ni) {
    float v = 0.f;
#pragma unroll
    for (int mi=0;mi<4;++mi)
#pragma unroll
      for (int jj=0;jj<4;++jj) v += f[mi][jj]*acc[mi][ni][jj];
    v += __shfl_xor(v, 16);
    v += __shfl_xor(v, 32);
    if (l4 == 0) atomicAdd(rb + wave*64 + ni*16 + l15, v);
  }
}

// ---------------- broadcast: out[b,n,:] = r[b,:] ----------------
__global__ __launch_bounds__(256) void bcast(const float* __restrict__ r, float* __restrict__ out) {
  size_t row = blockIdx.x;
  int b = (int)(row >> 8);
  f32x4 v = *(const f32x4*)(r + (size_t)b*1024 + threadIdx.x*4);
  *(f32x4*)(out + row*1024 + (size_t)threadIdx.x*4) = v;
}

extern "C" void kernel_launch(void* const* d_in, const int* in_sizes, int n_in,
                              void* d_out, int out_size, void* d_ws, size_t ws_size,
                              hipStream_t stream) {
  const float* x     = (const float*)d_in[0];
  const float* Wq    = (const float*)d_in[1];
  const float* Wkv   = (const float*)d_in[2];
  const float* Wout  = (const float*)d_in[3];
  const float* bout  = (const float*)d_in[4];
  const float* Wspec = (const float*)d_in[5];
  float* out = (float*)d_out;
  char* ws = (char*)d_ws;
  f16*   u16pad   = (f16*)(ws);
  float* logitbuf = (float*)(ws + 2097152);
  f16*   xbar     = (f16*)(ws + 3145728);
  float* qbuf     = (float*)(ws + 5242880);
  f16*   MT       = (f16*)(ws + 33554432);
  f16*   xT       = (f16*)(ws + 67108864);
  f16*   Wspec16  = (f16*)(ws + 102760448);
  float* attnout  = (float*)(ws + 103022592);
  float* spatial  = (float*)(ws + 103153664);
  float* rvec     = (float*)(ws + 103415808);
  (void)in_sizes; (void)n_in; (void)out_size; (void)ws_size;

  prep_xT     <<<dim3(32, 4, 64), dim3(256), 0, stream>>>(x, xT);
  prep_Wspec16<<<dim3(256),       dim3(256), 0, stream>>>(Wspec, Wspec16);
  gemm128<8,512,512,256,false><<<dim3(2, 2, 1), dim3(256), 0, stream>>>(Wspec16 + 256, Wspec16, MT, 0, 0, 0);
  qk          <<<dim3(64, 8),     dim3(256), 0, stream>>>(x, Wq, qbuf, attnout);
  uk          <<<dim3(8, 32),     dim3(256), 0, stream>>>(Wkv, qbuf, u16pad);
  lgk         <<<dim3(16, 64),    dim3(64),  0, stream>>>(x, u16pad, logitbuf);
  xbk         <<<dim3(64, 64),    dim3(64),  0, stream>>>(logitbuf, xT, xbar);
  vk          <<<dim3(8, 4, 8),   dim3(256), 0, stream>>>(xbar, Wkv, attnout);
  spatialf    <<<dim3(4, 64),     dim3(256), 0, stream>>>(attnout, Wout, bout, spatial, rvec);
  speck       <<<dim3(1024),      dim3(1024), 0, stream>>>(MT, xT, spatial, rvec);
  bcast       <<<dim3(16384),     dim3(256), 0, stream>>>(rvec, out);
}